// Round 8
// baseline (5194.610 us; speedup 1.0000x reference)
//
#include <hip/hip_runtime.h>
#include <math.h>

#define S_LEN 32
#define B_N   16
#define H_N   1024
#define E_N   256
#define V_N   32000
#define KBEAM 4
#define DIN   1536
#define D2    2560   // DIN + H_N
#define R_N   64     // KBEAM * B_N rows of state
#define NDS   8      // K-slices for gates GEMM (320 each)
#define NB    500    // stats col-blocks = V_N/64
#define LKS   4      // logits K-split
#define LCB   125    // logits col-blocks = V_N/256

__device__ __forceinline__ float sigmf(float x){ return 1.0f/(1.0f+expf(-x)); }
__device__ __forceinline__ bool better(float v1,int i1,float v2,int i2){
  return (v1>v2) || (v1==v2 && i1<i2);
}
// insert candidate (bv,bi) into sorted-desc top-4 (av0 best)
__device__ __forceinline__ void ins4(float bv,int bi,
    float&av0,float&av1,float&av2,float&av3,int&ai0,int&ai1,int&ai2,int&ai3){
  if (better(bv,bi,av3,ai3)){ av3=bv; ai3=bi;
    if (better(av3,ai3,av2,ai2)){ float t=av2;av2=av3;av3=t; int q=ai2;ai2=ai3;ai3=q;
      if (better(av2,ai2,av1,ai1)){ t=av1;av1=av2;av2=t; q=ai1;ai1=ai2;ai2=q;
        if (better(av1,ai1,av0,ai0)){ t=av0;av0=av1;av1=t; q=ai0;ai0=ai1;ai1=q; } } } }
}

// 4x4 FMA micro-tile into acc[4][4]
#define FMA16(w4, h4) { \
  acc[0][0]=fmaf(w4.x,h4.x,acc[0][0]); acc[0][1]=fmaf(w4.x,h4.y,acc[0][1]); \
  acc[0][2]=fmaf(w4.x,h4.z,acc[0][2]); acc[0][3]=fmaf(w4.x,h4.w,acc[0][3]); \
  acc[1][0]=fmaf(w4.y,h4.x,acc[1][0]); acc[1][1]=fmaf(w4.y,h4.y,acc[1][1]); \
  acc[1][2]=fmaf(w4.y,h4.z,acc[1][2]); acc[1][3]=fmaf(w4.y,h4.w,acc[1][3]); \
  acc[2][0]=fmaf(w4.z,h4.x,acc[2][0]); acc[2][1]=fmaf(w4.z,h4.y,acc[2][1]); \
  acc[2][2]=fmaf(w4.z,h4.z,acc[2][2]); acc[2][3]=fmaf(w4.z,h4.w,acc[2][3]); \
  acc[3][0]=fmaf(w4.w,h4.x,acc[3][0]); acc[3][1]=fmaf(w4.w,h4.y,acc[3][1]); \
  acc[3][2]=fmaf(w4.w,h4.z,acc[3][2]); acc[3][3]=fmaf(w4.w,h4.w,acc[3][3]); }

// 4x4 FMA micro-tile into acc[CO..CO+3][RO..RO+3] (for the 8x8 kernel)
#define FMA4x4(w4, h4, CO, RO) { \
  acc[CO+0][RO+0]=fmaf(w4.x,h4.x,acc[CO+0][RO+0]); acc[CO+0][RO+1]=fmaf(w4.x,h4.y,acc[CO+0][RO+1]); \
  acc[CO+0][RO+2]=fmaf(w4.x,h4.z,acc[CO+0][RO+2]); acc[CO+0][RO+3]=fmaf(w4.x,h4.w,acc[CO+0][RO+3]); \
  acc[CO+1][RO+0]=fmaf(w4.y,h4.x,acc[CO+1][RO+0]); acc[CO+1][RO+1]=fmaf(w4.y,h4.y,acc[CO+1][RO+1]); \
  acc[CO+1][RO+2]=fmaf(w4.y,h4.z,acc[CO+1][RO+2]); acc[CO+1][RO+3]=fmaf(w4.y,h4.w,acc[CO+1][RO+3]); \
  acc[CO+2][RO+0]=fmaf(w4.z,h4.x,acc[CO+2][RO+0]); acc[CO+2][RO+1]=fmaf(w4.z,h4.y,acc[CO+2][RO+1]); \
  acc[CO+2][RO+2]=fmaf(w4.z,h4.z,acc[CO+2][RO+2]); acc[CO+2][RO+3]=fmaf(w4.z,h4.w,acc[CO+2][RO+3]); \
  acc[CO+3][RO+0]=fmaf(w4.w,h4.x,acc[CO+3][RO+0]); acc[CO+3][RO+1]=fmaf(w4.w,h4.y,acc[CO+3][RO+1]); \
  acc[CO+3][RO+2]=fmaf(w4.w,h4.z,acc[CO+3][RO+2]); acc[CO+3][RO+3]=fmaf(w4.w,h4.w,acc[CO+3][RO+3]); }

// ---- init: x0 = [embed[START] | enc_inputs[0] | enc_outputs[0]] , c0
__global__ __launch_bounds__(256) void k_init(
    const float* __restrict__ enc_h_n, const float* __restrict__ enc_c_n,
    const float* __restrict__ enc_outputs, const float* __restrict__ enc_inputs,
    const float* __restrict__ embed, float* __restrict__ x, float* __restrict__ c){
  int r = blockIdx.x, tid = threadIdx.x, b = r & 15;
  float* xr = x + (size_t)r*D2;
  xr[tid]        = embed[E_N + tid];                 // START token = 1
  xr[E_N + tid]  = enc_inputs[b*E_N + tid];          // t = 0
  #pragma unroll
  for (int q=0;q<4;++q) xr[2*E_N + q*256 + tid] = enc_outputs[b*H_N + q*256 + tid];
  #pragma unroll
  for (int q=0;q<4;++q) xr[DIN + q*256 + tid]   = enc_h_n[b*H_N + q*256 + tid];
  #pragma unroll
  for (int q=0;q<4;++q) c[(size_t)r*H_N + q*256 + tid] = enc_c_n[b*H_N + q*256 + tid];
}

// ---- gates GEMM (LDS double-buffered, 1 barrier/chunk): gpart[ks][64][4096]
// grid (64 col-tiles x 8 K-slices), 256 thr. Block: 64 cols x 64 rows, K=320.
#define GWLD(d, off) (*(const float4*)((((d) < DIN) ? (w_ih + (size_t)(d)*4096) \
                       : (w_hh + (size_t)((d)-DIN)*4096)) + (off)))
__global__ __launch_bounds__(256) void k_gates(
    const float* __restrict__ x, const float* __restrict__ w_ih,
    const float* __restrict__ w_hh, float* __restrict__ gpart){
  int tid = threadIdx.x;
  int jt = blockIdx.x, ks = blockIdx.y;
  int cx = tid & 15, ry = tid >> 4;
  int cb = jt*64;
  int wdd = tid >> 4, wseg = tid & 15;   // W stage: 16 dd x 16 col-segs (x2)
  int xrow = tid >> 3, xseg = tid & 7;   // X stage: 32 rows x 8 dd-segs (x2)

  __shared__ float Wt0[32][64], Wt1[32][64];
  __shared__ float Xt0[32][68], Xt1[32][68];

  float acc[4][4];
  #pragma unroll
  for (int cc=0;cc<4;++cc)
    #pragma unroll
    for (int rr=0;rr<4;++rr) acc[cc][rr]=0.f;

  int d0 = ks*320;                       // NCH = 10 chunks of 32
  const float* xp0 = x + (size_t)xrow*D2 + d0 + xseg*4;
  const float* xp1 = x + (size_t)(xrow+32)*D2 + d0 + xseg*4;

#define GLQ(WA,WB,X0,X1, ch) { int d_ = d0 + (ch)*32; \
  WA = GWLD(d_+wdd,    cb+wseg*4); \
  WB = GWLD(d_+16+wdd, cb+wseg*4); \
  X0 = *(const float4*)(xp0 + (ch)*32); \
  X1 = *(const float4*)(xp1 + (ch)*32); }
#define GSQ(Wt,Xt, WA,WB,X0,X1) { \
  *(float4*)&Wt[wdd][wseg*4]    = WA; \
  *(float4*)&Wt[wdd+16][wseg*4] = WB; \
  Xt[xseg*4+0][xrow] = X0.x; Xt[xseg*4+1][xrow] = X0.y; \
  Xt[xseg*4+2][xrow] = X0.z; Xt[xseg*4+3][xrow] = X0.w; \
  Xt[xseg*4+0][xrow+32] = X1.x; Xt[xseg*4+1][xrow+32] = X1.y; \
  Xt[xseg*4+2][xrow+32] = X1.z; Xt[xseg*4+3][xrow+32] = X1.w; }
#define GCQ(Wt,Xt) { _Pragma("unroll 8") for (int dd=0; dd<32; ++dd){ \
    float4 w4 = *(const float4*)&Wt[dd][cx*4]; \
    float4 h4 = *(const float4*)&Xt[dd][ry*4]; \
    FMA16(w4, h4) } }

  float4 wA0,wB0,x00,x10, wA1,wB1,x01,x11;
  GLQ(wA0,wB0,x00,x10, 0)
  GSQ(Wt0,Xt0, wA0,wB0,x00,x10)
  GLQ(wA1,wB1,x01,x11, 1)
  __syncthreads();

  for (int ch=0; ch<10; ch+=2){
    if (ch+2<10) GLQ(wA0,wB0,x00,x10, ch+2)
    GSQ(Wt1,Xt1, wA1,wB1,x01,x11)
    GCQ(Wt0,Xt0)
    __syncthreads();
    if (ch+3<10) GLQ(wA1,wB1,x01,x11, ch+3)
    if (ch+2<10) GSQ(Wt0,Xt0, wA0,wB0,x00,x10)
    GCQ(Wt1,Xt1)
    if (ch+2<10) __syncthreads();
  }
  #pragma unroll
  for (int rr=0;rr<4;++rr){
    float4 o; o.x=acc[0][rr]; o.y=acc[1][rr]; o.z=acc[2][rr]; o.w=acc[3][rr];
    *(float4*)&gpart[((size_t)(ks*R_N + ry*4+rr))*4096 + cb + cx*4] = o;
  }
}

// ---- LSTM: sum partials + bias, cell update; h2 -> xn[.,1536:] and h2t[1024][64]
__global__ __launch_bounds__(256) void k_lstm(
    const float* __restrict__ gpart, const float* __restrict__ b_lstm,
    float* __restrict__ c, float* __restrict__ xn, float* __restrict__ h2t){
  int r = blockIdx.x, tid = threadIdx.x;
  #pragma unroll
  for (int it=0; it<4; ++it){
    int j = it*256 + tid;
    float gi = b_lstm[j], gf = b_lstm[1024+j], gg = b_lstm[2048+j], go = b_lstm[3072+j];
    #pragma unroll
    for (int ds=0; ds<NDS; ++ds){
      size_t base = ((size_t)ds*R_N + r)*4096;
      gi += gpart[base + j];      gf += gpart[base + 1024 + j];
      gg += gpart[base + 2048+j]; go += gpart[base + 3072 + j];
    }
    float cv = c[(size_t)r*H_N + j];
    float c2 = sigmf(gf)*cv + sigmf(gi)*tanhf(gg);
    float h2 = sigmf(go)*tanhf(c2);
    c[(size_t)r*H_N + j] = c2;
    xn[(size_t)r*D2 + DIN + j] = h2;
    h2t[(size_t)j*R_N + r] = h2;
  }
}

// ---- logits GEMM, K-split x4, 8x8 thread tile -> plog[4][64][32000]
// grid (125, 4) x 256 thr. Block: 256 cols x 64 rows x 256 dd.
// Chunks of 16 dd; Wt[16][256] + Ht[16][64], dbuf, 1 barrier/chunk.
// Thread: 8 cols (cg) x 8 rows (rg). LDS: W unique-read 32B/dd, H broadcast.
__global__ __launch_bounds__(256) void k_logits_split(
    const float* __restrict__ h2t, const float* __restrict__ w_out,
    float* __restrict__ plog){
  int tid = threadIdx.x;
  int cg = tid & 31;          // col group: cols cb + cg*8 .. +7
  int rg = tid >> 5;          // row group: rows rg*8 .. +7
  int cb = blockIdx.x * 256;
  int ks = blockIdx.y;
  int srow = tid >> 4, scol = tid & 15;   // staging: 16 dd-rows x 16 segs

  __shared__ float Wt0[16][256], Wt1[16][256];
  __shared__ float Ht0[16][64],  Ht1[16][64];

  float acc[8][8];
  #pragma unroll
  for (int cc=0;cc<8;++cc)
    #pragma unroll
    for (int rr=0;rr<8;++rr) acc[cc][rr]=0.f;

  const float* gW = w_out + (size_t)(ks*256 + srow)*V_N + cb + scol*16;
  const float* gH = h2t + (size_t)(ks*256 + srow)*64 + scol*4;

#define LLQ(WR, HR, ch) { \
  const float* gWn = gW + (size_t)(ch)*16*V_N; \
  const float* gHn = gH + (size_t)(ch)*16*64; \
  WR[0]=*(const float4*)(gWn);   WR[1]=*(const float4*)(gWn+4); \
  WR[2]=*(const float4*)(gWn+8); WR[3]=*(const float4*)(gWn+12); \
  HR = *(const float4*)(gHn); }
#define LSQ(Wt, Ht, WR, HR) { \
  *(float4*)&Wt[srow][scol*16+ 0] = WR[0]; \
  *(float4*)&Wt[srow][scol*16+ 4] = WR[1]; \
  *(float4*)&Wt[srow][scol*16+ 8] = WR[2]; \
  *(float4*)&Wt[srow][scol*16+12] = WR[3]; \
  *(float4*)&Ht[srow][scol*4]     = HR; }
#define LCQ(Wt, Ht) { _Pragma("unroll 4") for (int dd=0; dd<16; ++dd){ \
    float4 wa = *(const float4*)&Wt[dd][cg*8]; \
    float4 wb = *(const float4*)&Wt[dd][cg*8+4]; \
    float4 ha = *(const float4*)&Ht[dd][rg*8]; \
    float4 hb = *(const float4*)&Ht[dd][rg*8+4]; \
    FMA4x4(wa,ha,0,0) FMA4x4(wa,hb,0,4) FMA4x4(wb,ha,4,0) FMA4x4(wb,hb,4,4) } }

  float4 w0[4], w1[4], h0, h1;
  LLQ(w0, h0, 0)
  LSQ(Wt0, Ht0, w0, h0)
  LLQ(w1, h1, 1)
  __syncthreads();

  for (int ch=0; ch<16; ch+=2){
    if (ch+2<16) LLQ(w0, h0, ch+2)
    LSQ(Wt1, Ht1, w1, h1)
    LCQ(Wt0, Ht0)
    __syncthreads();
    if (ch+3<16) LLQ(w1, h1, ch+3)
    if (ch+2<16) LSQ(Wt0, Ht0, w0, h0)
    LCQ(Wt1, Ht1)
    if (ch+2<16) __syncthreads();
  }

  #pragma unroll
  for (int rr=0;rr<8;++rr){
    float4 o1, o2;
    o1.x=acc[0][rr]; o1.y=acc[1][rr]; o1.z=acc[2][rr]; o1.w=acc[3][rr];
    o2.x=acc[4][rr]; o2.y=acc[5][rr]; o2.z=acc[6][rr]; o2.w=acc[7][rr];
    float* dst = &plog[((size_t)ks*R_N + rg*8+rr)*V_N + cb + cg*8];
    *(float4*)dst = o1; *(float4*)(dst+4) = o2;
  }
}

// ---- stats: sum the four K-slices + bias, per-row softmax stats & top-4.
// 500 blocks x 256 thr; 64-col tiles; width-16 butterfly.
__global__ __launch_bounds__(256) void k_stats(
    const float* __restrict__ plog, const float* __restrict__ b_out,
    float* __restrict__ pm, float* __restrict__ pz,
    float* __restrict__ pv, int* __restrict__ pi){
  int tid = threadIdx.x;
  int cx = tid & 15, ry = tid >> 4;
  int cb = blockIdx.x * 64;
  float4 bias = *(const float4*)&b_out[cb + cx*4];
  #pragma unroll
  for (int rr=0;rr<4;++rr){
    int row = ry*4 + rr;
    float4 a0 = *(const float4*)&plog[((size_t)0*R_N+row)*V_N + cb + cx*4];
    float4 a1 = *(const float4*)&plog[((size_t)1*R_N+row)*V_N + cb + cx*4];
    float4 a2 = *(const float4*)&plog[((size_t)2*R_N+row)*V_N + cb + cx*4];
    float4 a3 = *(const float4*)&plog[((size_t)3*R_N+row)*V_N + cb + cx*4];
    float v0 = a0.x+a1.x+a2.x+a3.x+bias.x;
    float v1 = a0.y+a1.y+a2.y+a3.y+bias.y;
    float v2 = a0.z+a1.z+a2.z+a3.z+bias.z;
    float v3 = a0.w+a1.w+a2.w+a3.w+bias.w;
    int   c0i = cb + cx*4;
    float tv0=-INFINITY,tv1=-INFINITY,tv2=-INFINITY,tv3=-INFINITY;
    int   ti0=0x7fffffff,ti1=0x7fffffff,ti2=0x7fffffff,ti3=0x7fffffff;
    ins4(v0,c0i+0,tv0,tv1,tv2,tv3,ti0,ti1,ti2,ti3);
    ins4(v1,c0i+1,tv0,tv1,tv2,tv3,ti0,ti1,ti2,ti3);
    ins4(v2,c0i+2,tv0,tv1,tv2,tv3,ti0,ti1,ti2,ti3);
    ins4(v3,c0i+3,tv0,tv1,tv2,tv3,ti0,ti1,ti2,ti3);
    float z = expf(v0-tv0)+expf(v1-tv0)+expf(v2-tv0)+expf(v3-tv0);
    #pragma unroll
    for (int msk=1; msk<16; msk<<=1){
      float om  = __shfl_xor(tv0, msk, 16);
      float oz  = __shfl_xor(z,   msk, 16);
      float ov1 = __shfl_xor(tv1, msk, 16);
      float ov2 = __shfl_xor(tv2, msk, 16);
      float ov3 = __shfl_xor(tv3, msk, 16);
      int   oi0 = __shfl_xor(ti0, msk, 16);
      int   oi1 = __shfl_xor(ti1, msk, 16);
      int   oi2 = __shfl_xor(ti2, msk, 16);
      int   oi3 = __shfl_xor(ti3, msk, 16);
      float M = fmaxf(tv0, om);
      z = z*expf(tv0-M) + oz*expf(om-M);
      ins4(om, oi0, tv0,tv1,tv2,tv3, ti0,ti1,ti2,ti3);
      ins4(ov1,oi1, tv0,tv1,tv2,tv3, ti0,ti1,ti2,ti3);
      ins4(ov2,oi2, tv0,tv1,tv2,tv3, ti0,ti1,ti2,ti3);
      ins4(ov3,oi3, tv0,tv1,tv2,tv3, ti0,ti1,ti2,ti3);
    }
    if (cx == 0){
      size_t base = (size_t)row*NB + blockIdx.x;   // [row][block]
      pm[base]=tv0; pz[base]=z;
      pv[base*4+0]=tv0; pv[base*4+1]=tv1; pv[base*4+2]=tv2; pv[base*4+3]=tv3;
      pi[base*4+0]=ti0; pi[base*4+1]=ti1; pi[base*4+2]=ti2; pi[base*4+3]=ti3;
    }
  }
}

// ---- fallback: fused logits+stats (round-6 kernel), used if ws too small.
__global__ __launch_bounds__(256) void k_logits_fused(
    const float* __restrict__ h2t, const float* __restrict__ w_out,
    const float* __restrict__ b_out,
    float* __restrict__ pm, float* __restrict__ pz,
    float* __restrict__ pv, int* __restrict__ pi){
  int tid = threadIdx.x;
  int cx  = tid & 15, ry = tid >> 4;
  int cb  = blockIdx.x * 64;
  int sdd = tid >> 4, seg = tid & 15;
  __shared__ float Wt[32][64];
  __shared__ float Ht[32][64];
  float acc[4][4];
  #pragma unroll
  for (int cc=0;cc<4;++cc)
    #pragma unroll
    for (int rr=0;rr<4;++rr) acc[cc][rr]=0.f;
  const float* gW = w_out + (size_t)sdd*V_N + cb + seg*4;
  const float* gH = h2t + sdd*64 + seg*4;
#define FLQ(WA,WB,HA,HB, ch) { \
  const float* gWn = gW + (size_t)(ch)*32*V_N; \
  const float* gHn = gH + (size_t)(ch)*32*64; \
  WA = *(const float4*)gWn; WB = *(const float4*)(gWn + (size_t)16*V_N); \
  HA = *(const float4*)gHn; HB = *(const float4*)(gHn + 16*64); }
#define FSQ(WA,WB,HA,HB) { \
  *(float4*)&Wt[sdd][seg*4]    = WA; \
  *(float4*)&Wt[sdd+16][seg*4] = WB; \
  *(float4*)&Ht[sdd][seg*4]    = HA; \
  *(float4*)&Ht[sdd+16][seg*4] = HB; }
#define FCQ() { _Pragma("unroll 8") for (int dd=0; dd<32; ++dd){ \
    float4 w4 = *(const float4*)&Wt[dd][cx*4]; \
    float4 h4 = *(const float4*)&Ht[dd][ry*4]; \
    FMA16(w4, h4) } }
  float4 wA0,wB0,hA0,hB0, wA1,wB1,hA1,hB1;
  FLQ(wA0,wB0,hA0,hB0, 0)
  FSQ(wA0,wB0,hA0,hB0)
  FLQ(wA1,wB1,hA1,hB1, 1)
  __syncthreads();
  for (int ch=0; ch<32; ch+=2){
    if (ch+2<32) FLQ(wA0,wB0,hA0,hB0, ch+2)
    FCQ()
    __syncthreads();
    FSQ(wA1,wB1,hA1,hB1)
    __syncthreads();
    if (ch+3<32) FLQ(wA1,wB1,hA1,hB1, ch+3)
    FCQ()
    if (ch+2<32){
      __syncthreads();
      FSQ(wA0,wB0,hA0,hB0)
      __syncthreads();
    }
  }
  float4 bias = *(const float4*)&b_out[cb + cx*4];
  #pragma unroll
  for (int rr=0;rr<4;++rr){
    float v0 = acc[0][rr]+bias.x, v1 = acc[1][rr]+bias.y;
    float v2 = acc[2][rr]+bias.z, v3 = acc[3][rr]+bias.w;
    int   c0i = cb + cx*4;
    float tv0=-INFINITY,tv1=-INFINITY,tv2=-INFINITY,tv3=-INFINITY;
    int   ti0=0x7fffffff,ti1=0x7fffffff,ti2=0x7fffffff,ti3=0x7fffffff;
    ins4(v0,c0i+0,tv0,tv1,tv2,tv3,ti0,ti1,ti2,ti3);
    ins4(v1,c0i+1,tv0,tv1,tv2,tv3,ti0,ti1,ti2,ti3);
    ins4(v2,c0i+2,tv0,tv1,tv2,tv3,ti0,ti1,ti2,ti3);
    ins4(v3,c0i+3,tv0,tv1,tv2,tv3,ti0,ti1,ti2,ti3);
    float z = expf(v0-tv0)+expf(v1-tv0)+expf(v2-tv0)+expf(v3-tv0);
    #pragma unroll
    for (int msk=1; msk<16; msk<<=1){
      float om  = __shfl_xor(tv0, msk, 16);
      float oz  = __shfl_xor(z,   msk, 16);
      float ov1 = __shfl_xor(tv1, msk, 16);
      float ov2 = __shfl_xor(tv2, msk, 16);
      float ov3 = __shfl_xor(tv3, msk, 16);
      int   oi0 = __shfl_xor(ti0, msk, 16);
      int   oi1 = __shfl_xor(ti1, msk, 16);
      int   oi2 = __shfl_xor(ti2, msk, 16);
      int   oi3 = __shfl_xor(ti3, msk, 16);
      float M = fmaxf(tv0, om);
      z = z*expf(tv0-M) + oz*expf(om-M);
      ins4(om, oi0, tv0,tv1,tv2,tv3, ti0,ti1,ti2,ti3);
      ins4(ov1,oi1, tv0,tv1,tv2,tv3, ti0,ti1,ti2,ti3);
      ins4(ov2,oi2, tv0,tv1,tv2,tv3, ti0,ti1,ti2,ti3);
      ins4(ov3,oi3, tv0,tv1,tv2,tv3, ti0,ti1,ti2,ti3);
    }
    if (cx == 0){
      int row = ry*4 + rr;
      size_t base = (size_t)row*NB + blockIdx.x;
      pm[base]=tv0; pz[base]=z;
      pv[base*4+0]=tv0; pv[base*4+1]=tv1; pv[base*4+2]=tv2; pv[base*4+3]=tv3;
      pi[base*4+0]=ti0; pi[base*4+1]=ti1; pi[base*4+2]=ti2; pi[base*4+3]=ti3;
    }
  }
}

// ---- final: reduce NB partials per row, joint top-4 per b, write out, next-x.
__global__ __launch_bounds__(256) void k_final(
    const float* __restrict__ pm, const float* __restrict__ pz,
    const float* __restrict__ pv, const int* __restrict__ pi,
    float* __restrict__ scores, int* __restrict__ out, int t,
    float* __restrict__ xn,
    const float* __restrict__ enc_inputs, const float* __restrict__ enc_outputs,
    const float* __restrict__ embed){
  int b = blockIdx.x, tid = threadIdx.x;
  __shared__ float sm[256], sz[256], stv[1024];
  __shared__ int   sti[1024];
  __shared__ float fM[KBEAM], fZ[KBEAM], fV[16];
  __shared__ int   fI[16], sw[KBEAM];
  int nk = (t==0) ? 1 : KBEAM;
  for (int k=0;k<nk;++k){
    size_t rb = (size_t)(k*B_N + b)*NB;
    float m=-INFINITY, z=0.f;
    float av0=-INFINITY,av1=-INFINITY,av2=-INFINITY,av3=-INFINITY;
    int   ai0=0x7fffffff,ai1=0x7fffffff,ai2=0x7fffffff,ai3=0x7fffffff;
    for (int p0=tid; p0<NB; p0+=256){
      size_t p = rb + p0;
      float mf = pm[p];
      float M = fmaxf(m, mf);
      z = z*expf(m-M) + pz[p]*expf(mf-M);
      m = M;
      #pragma unroll
      for (int q=0;q<4;++q)
        ins4(pv[p*4+q], pi[p*4+q], av0,av1,av2,av3, ai0,ai1,ai2,ai3);
    }
    sm[tid]=m; sz[tid]=z;
    stv[tid*4+0]=av0; stv[tid*4+1]=av1; stv[tid*4+2]=av2; stv[tid*4+3]=av3;
    sti[tid*4+0]=ai0; sti[tid*4+1]=ai1; sti[tid*4+2]=ai2; sti[tid*4+3]=ai3;
    __syncthreads();
    for (int off=128; off>0; off>>=1){
      if (tid<off){
        float ma=sm[tid], mb=sm[tid+off];
        float za=sz[tid], zb=sz[tid+off];
        float M = fmaxf(ma,mb);
        sz[tid] = za*expf(ma-M) + zb*expf(mb-M);
        sm[tid] = M;
        float bv0=stv[tid*4],bv1=stv[tid*4+1],bv2=stv[tid*4+2],bv3=stv[tid*4+3];
        int   bi0=sti[tid*4],bi1=sti[tid*4+1],bi2=sti[tid*4+2],bi3=sti[tid*4+3];
        #pragma unroll
        for (int q=0;q<4;++q)
          ins4(stv[(tid+off)*4+q], sti[(tid+off)*4+q],
               bv0,bv1,bv2,bv3, bi0,bi1,bi2,bi3);
        stv[tid*4]=bv0; stv[tid*4+1]=bv1; stv[tid*4+2]=bv2; stv[tid*4+3]=bv3;
        sti[tid*4]=bi0; sti[tid*4+1]=bi1; sti[tid*4+2]=bi2; sti[tid*4+3]=bi3;
      }
      __syncthreads();
    }
    if (tid==0){
      fM[k]=sm[0]; fZ[k]=sz[0];
      fV[k*4+0]=stv[0]; fV[k*4+1]=stv[1]; fV[k*4+2]=stv[2]; fV[k*4+3]=stv[3];
      fI[k*4+0]=sti[0]; fI[k*4+1]=sti[1]; fI[k*4+2]=sti[2]; fI[k*4+3]=sti[3];
    }
    __syncthreads();
  }
  if (tid==0){
    if (t==0){
      #pragma unroll
      for (int j=0;j<4;++j){
        float p = expf(fV[j]-fM[0])/fZ[0];
        scores[b*4+j] = p;
        out[j*(B_N*S_LEN) + b*S_LEN] = fI[j];
        sw[j] = fI[j];
      }
    } else {
      float cv[16]; int cj[16];
      for (int k=0;k<4;++k){
        float s = scores[b*4+k];
        #pragma unroll
        for (int j=0;j<4;++j){
          cv[k*4+j] = expf(fV[k*4+j]-fM[k])/fZ[k]*s;
          cj[k*4+j] = k*V_N + fI[k*4+j];
        }
      }
      bool used[16];
      for (int i=0;i<16;++i) used[i]=false;
      for (int rank=0;rank<4;++rank){
        int best=-1;
        for (int i=0;i<16;++i){
          if (used[i]) continue;
          if (best<0 || cv[i]>cv[best] || (cv[i]==cv[best] && cj[i]<cj[best])) best=i;
        }
        used[best]=true;
        out[rank*(B_N*S_LEN) + b*S_LEN + t] = cj[best];
        sw[rank] = cj[best] % V_N;
      }
    }
  }
  __syncthreads();
  if (t < S_LEN-1){
    const float* ein = enc_inputs  + (size_t)(t+1)*B_N*E_N + (size_t)b*E_N;
    const float* eo  = enc_outputs + (size_t)(t+1)*B_N*H_N + (size_t)b*H_N;
    #pragma unroll
    for (int j=0;j<KBEAM;++j){
      float* xr = xn + (size_t)(j*B_N + b)*D2;
      const float* em = embed + (size_t)sw[j]*E_N;
      xr[tid]       = em[tid];
      xr[E_N + tid] = ein[tid];
      #pragma unroll
      for (int q=0;q<4;++q) xr[2*E_N + q*256 + tid] = eo[q*256 + tid];
    }
  }
}

extern "C" void kernel_launch(void* const* d_in, const int* in_sizes, int n_in,
                              void* d_out, int out_size, void* d_ws, size_t ws_size,
                              hipStream_t stream) {
  (void)in_sizes; (void)n_in; (void)out_size;
  const float* enc_h_n     = (const float*)d_in[0];
  const float* enc_c_n     = (const float*)d_in[1];
  const float* enc_outputs = (const float*)d_in[2];
  const float* enc_inputs  = (const float*)d_in[3];
  const float* embed       = (const float*)d_in[4];
  const float* w_ih        = (const float*)d_in[5];
  const float* w_hh        = (const float*)d_in[6];
  const float* b_lstm      = (const float*)d_in[7];
  const float* w_out       = (const float*)d_in[8];
  const float* b_out       = (const float*)d_in[9];
  int* out = (int*)d_out;

  float* ws = (float*)d_ws;
  const size_t FRONTF = (size_t)R_N*D2*2 + (size_t)R_N*H_N + (size_t)H_N*R_N; // 458752
  const size_t PLOGF  = (size_t)LKS*R_N*V_N;    // 8,192,000
  const size_t GPARTF = (size_t)NDS*R_N*4096;   // 2,097,152
  const size_t STATF  = (size_t)R_N*NB*10;      // 320,000
  size_t need_split = (FRONTF + PLOGF + STATF + 64)*sizeof(float);
  bool use_split = (ws_size >= need_split);

  float* xA     = ws;
  float* xB     = xA + (size_t)R_N*D2;
  float* cbuf   = xB + (size_t)R_N*D2;
  float* h2t    = cbuf + (size_t)R_N*H_N;
  float* big    = h2t + (size_t)H_N*R_N;
  float* gpart  = big;                       // lifetime: k_gates -> k_lstm
  float* plog   = big;                       // lifetime: k_logits_split -> k_stats
  float *pm, *pz, *pv, *scoresb; int *pi;
  if (use_split){
    pm = big + PLOGF;
    pz = pm + (size_t)R_N*NB;
    pv = pz + (size_t)R_N*NB;
    pi = (int*)(pv + (size_t)R_N*NB*4);
    scoresb = (float*)(pi + (size_t)R_N*NB*4);
  } else {
    pm = big;                                // aliased inside gpart (disjoint lifetime)
    pz = pm + (size_t)R_N*NB;
    pv = pz + (size_t)R_N*NB;
    pi = (int*)(pv + (size_t)R_N*NB*4);
    scoresb = big + GPARTF;
  }

  k_init<<<R_N, 256, 0, stream>>>(enc_h_n, enc_c_n, enc_outputs, enc_inputs, embed, xA, cbuf);

  for (int t=0; t<S_LEN; ++t){
    float* xc = (t & 1) ? xB : xA;
    float* xn = (t & 1) ? xA : xB;
    k_gates <<<dim3(64, NDS), 256, 0, stream>>>(xc, w_ih, w_hh, gpart);
    k_lstm  <<<R_N, 256, 0, stream>>>(gpart, b_lstm, cbuf, xn, h2t);
    if (use_split){
      k_logits_split<<<dim3(LCB, LKS), 256, 0, stream>>>(h2t, w_out, plog);
      k_stats<<<NB, 256, 0, stream>>>(plog, b_out, pm, pz, pv, pi);
    } else {
      k_logits_fused<<<NB, 256, 0, stream>>>(h2t, w_out, b_out, pm, pz, pv, pi);
    }
    k_final <<<B_N, 256, 0, stream>>>(pm, pz, pv, pi, scoresb, out, t, xn,
                                      enc_inputs, enc_outputs, embed);
  }
}

// Round 9
// 5152.704 us; speedup vs baseline: 1.0081x; 1.0081x over previous
//
#include <hip/hip_runtime.h>
#include <math.h>

#define S_LEN 32
#define B_N   16
#define H_N   1024
#define E_N   256
#define V_N   32000
#define KBEAM 4
#define DIN   1536
#define D2    2560   // DIN + H_N
#define R_N   64     // KBEAM * B_N rows of state
#define NDS   8      // K-slices for gates GEMM (320 each)
#define NB    500    // stats col-blocks = V_N/64
#define LKS   4      // logits K-split
#define LCB   125    // logits col-blocks = V_N/256

__device__ __forceinline__ float sigmf(float x){ return 1.0f/(1.0f+expf(-x)); }
__device__ __forceinline__ bool better(float v1,int i1,float v2,int i2){
  return (v1>v2) || (v1==v2 && i1<i2);
}
// insert candidate (bv,bi) into sorted-desc top-4 (av0 best)
__device__ __forceinline__ void ins4(float bv,int bi,
    float&av0,float&av1,float&av2,float&av3,int&ai0,int&ai1,int&ai2,int&ai3){
  if (better(bv,bi,av3,ai3)){ av3=bv; ai3=bi;
    if (better(av3,ai3,av2,ai2)){ float t=av2;av2=av3;av3=t; int q=ai2;ai2=ai3;ai3=q;
      if (better(av2,ai2,av1,ai1)){ t=av1;av1=av2;av2=t; q=ai1;ai1=ai2;ai2=q;
        if (better(av1,ai1,av0,ai0)){ t=av0;av0=av1;av1=t; q=ai0;ai0=ai1;ai1=q; } } } }
}

// 4x4 FMA micro-tile into acc[4][4]
#define FMA16(w4, h4) { \
  acc[0][0]=fmaf(w4.x,h4.x,acc[0][0]); acc[0][1]=fmaf(w4.x,h4.y,acc[0][1]); \
  acc[0][2]=fmaf(w4.x,h4.z,acc[0][2]); acc[0][3]=fmaf(w4.x,h4.w,acc[0][3]); \
  acc[1][0]=fmaf(w4.y,h4.x,acc[1][0]); acc[1][1]=fmaf(w4.y,h4.y,acc[1][1]); \
  acc[1][2]=fmaf(w4.y,h4.z,acc[1][2]); acc[1][3]=fmaf(w4.y,h4.w,acc[1][3]); \
  acc[2][0]=fmaf(w4.z,h4.x,acc[2][0]); acc[2][1]=fmaf(w4.z,h4.y,acc[2][1]); \
  acc[2][2]=fmaf(w4.z,h4.z,acc[2][2]); acc[2][3]=fmaf(w4.z,h4.w,acc[2][3]); \
  acc[3][0]=fmaf(w4.w,h4.x,acc[3][0]); acc[3][1]=fmaf(w4.w,h4.y,acc[3][1]); \
  acc[3][2]=fmaf(w4.w,h4.z,acc[3][2]); acc[3][3]=fmaf(w4.w,h4.w,acc[3][3]); }

// 4x4 FMA micro-tile into acc[CO..CO+3][RO..RO+3] (for the 8x8 kernel)
#define FMA4x4(w4, h4, CO, RO) { \
  acc[CO+0][RO+0]=fmaf(w4.x,h4.x,acc[CO+0][RO+0]); acc[CO+0][RO+1]=fmaf(w4.x,h4.y,acc[CO+0][RO+1]); \
  acc[CO+0][RO+2]=fmaf(w4.x,h4.z,acc[CO+0][RO+2]); acc[CO+0][RO+3]=fmaf(w4.x,h4.w,acc[CO+0][RO+3]); \
  acc[CO+1][RO+0]=fmaf(w4.y,h4.x,acc[CO+1][RO+0]); acc[CO+1][RO+1]=fmaf(w4.y,h4.y,acc[CO+1][RO+1]); \
  acc[CO+1][RO+2]=fmaf(w4.y,h4.z,acc[CO+1][RO+2]); acc[CO+1][RO+3]=fmaf(w4.y,h4.w,acc[CO+1][RO+3]); \
  acc[CO+2][RO+0]=fmaf(w4.z,h4.x,acc[CO+2][RO+0]); acc[CO+2][RO+1]=fmaf(w4.z,h4.y,acc[CO+2][RO+1]); \
  acc[CO+2][RO+2]=fmaf(w4.z,h4.z,acc[CO+2][RO+2]); acc[CO+2][RO+3]=fmaf(w4.z,h4.w,acc[CO+2][RO+3]); \
  acc[CO+3][RO+0]=fmaf(w4.w,h4.x,acc[CO+3][RO+0]); acc[CO+3][RO+1]=fmaf(w4.w,h4.y,acc[CO+3][RO+1]); \
  acc[CO+3][RO+2]=fmaf(w4.w,h4.z,acc[CO+3][RO+2]); acc[CO+3][RO+3]=fmaf(w4.w,h4.w,acc[CO+3][RO+3]); }

// ---- init: x0 = [embed[START] | enc_inputs[0] | enc_outputs[0]] , c0
__global__ __launch_bounds__(256) void k_init(
    const float* __restrict__ enc_h_n, const float* __restrict__ enc_c_n,
    const float* __restrict__ enc_outputs, const float* __restrict__ enc_inputs,
    const float* __restrict__ embed, float* __restrict__ x, float* __restrict__ c){
  int r = blockIdx.x, tid = threadIdx.x, b = r & 15;
  float* xr = x + (size_t)r*D2;
  xr[tid]        = embed[E_N + tid];                 // START token = 1
  xr[E_N + tid]  = enc_inputs[b*E_N + tid];          // t = 0
  #pragma unroll
  for (int q=0;q<4;++q) xr[2*E_N + q*256 + tid] = enc_outputs[b*H_N + q*256 + tid];
  #pragma unroll
  for (int q=0;q<4;++q) xr[DIN + q*256 + tid]   = enc_h_n[b*H_N + q*256 + tid];
  #pragma unroll
  for (int q=0;q<4;++q) c[(size_t)r*H_N + q*256 + tid] = enc_c_n[b*H_N + q*256 + tid];
}

// ---- gates GEMM (LDS double-buffered, 1 barrier/chunk): gpart[ks][64][4096]
// grid (64 col-tiles x 8 K-slices), 256 thr. Block: 64 cols x 64 rows, K=320.
#define GWLD(d, off) (*(const float4*)((((d) < DIN) ? (w_ih + (size_t)(d)*4096) \
                       : (w_hh + (size_t)((d)-DIN)*4096)) + (off)))
__global__ __launch_bounds__(256) void k_gates(
    const float* __restrict__ x, const float* __restrict__ w_ih,
    const float* __restrict__ w_hh, float* __restrict__ gpart){
  int tid = threadIdx.x;
  int jt = blockIdx.x, ks = blockIdx.y;
  int cx = tid & 15, ry = tid >> 4;
  int cb = jt*64;
  int wdd = tid >> 4, wseg = tid & 15;   // W stage: 16 dd x 16 col-segs (x2)
  int xrow = tid >> 3, xseg = tid & 7;   // X stage: 32 rows x 8 dd-segs (x2)

  __shared__ float Wt0[32][64], Wt1[32][64];
  __shared__ float Xt0[32][68], Xt1[32][68];

  float acc[4][4];
  #pragma unroll
  for (int cc=0;cc<4;++cc)
    #pragma unroll
    for (int rr=0;rr<4;++rr) acc[cc][rr]=0.f;

  int d0 = ks*320;                       // NCH = 10 chunks of 32
  const float* xp0 = x + (size_t)xrow*D2 + d0 + xseg*4;
  const float* xp1 = x + (size_t)(xrow+32)*D2 + d0 + xseg*4;

#define GLQ(WA,WB,X0,X1, ch) { int d_ = d0 + (ch)*32; \
  WA = GWLD(d_+wdd,    cb+wseg*4); \
  WB = GWLD(d_+16+wdd, cb+wseg*4); \
  X0 = *(const float4*)(xp0 + (ch)*32); \
  X1 = *(const float4*)(xp1 + (ch)*32); }
#define GSQ(Wt,Xt, WA,WB,X0,X1) { \
  *(float4*)&Wt[wdd][wseg*4]    = WA; \
  *(float4*)&Wt[wdd+16][wseg*4] = WB; \
  Xt[xseg*4+0][xrow] = X0.x; Xt[xseg*4+1][xrow] = X0.y; \
  Xt[xseg*4+2][xrow] = X0.z; Xt[xseg*4+3][xrow] = X0.w; \
  Xt[xseg*4+0][xrow+32] = X1.x; Xt[xseg*4+1][xrow+32] = X1.y; \
  Xt[xseg*4+2][xrow+32] = X1.z; Xt[xseg*4+3][xrow+32] = X1.w; }
#define GCQ(Wt,Xt) { _Pragma("unroll 8") for (int dd=0; dd<32; ++dd){ \
    float4 w4 = *(const float4*)&Wt[dd][cx*4]; \
    float4 h4 = *(const float4*)&Xt[dd][ry*4]; \
    FMA16(w4, h4) } }

  float4 wA0,wB0,x00,x10, wA1,wB1,x01,x11;
  GLQ(wA0,wB0,x00,x10, 0)
  GSQ(Wt0,Xt0, wA0,wB0,x00,x10)
  GLQ(wA1,wB1,x01,x11, 1)
  __syncthreads();

  for (int ch=0; ch<10; ch+=2){
    if (ch+2<10) GLQ(wA0,wB0,x00,x10, ch+2)
    GSQ(Wt1,Xt1, wA1,wB1,x01,x11)
    GCQ(Wt0,Xt0)
    __syncthreads();
    if (ch+3<10) GLQ(wA1,wB1,x01,x11, ch+3)
    if (ch+2<10) GSQ(Wt0,Xt0, wA0,wB0,x00,x10)
    GCQ(Wt1,Xt1)
    if (ch+2<10) __syncthreads();
  }
  #pragma unroll
  for (int rr=0;rr<4;++rr){
    float4 o; o.x=acc[0][rr]; o.y=acc[1][rr]; o.z=acc[2][rr]; o.w=acc[3][rr];
    *(float4*)&gpart[((size_t)(ks*R_N + ry*4+rr))*4096 + cb + cx*4] = o;
  }
}

// ---- LSTM: sum partials + bias, cell update; h2 -> xn[.,1536:] and h2t[1024][64]
__global__ __launch_bounds__(256) void k_lstm(
    const float* __restrict__ gpart, const float* __restrict__ b_lstm,
    float* __restrict__ c, float* __restrict__ xn, float* __restrict__ h2t){
  int r = blockIdx.x, tid = threadIdx.x;
  #pragma unroll
  for (int it=0; it<4; ++it){
    int j = it*256 + tid;
    float gi = b_lstm[j], gf = b_lstm[1024+j], gg = b_lstm[2048+j], go = b_lstm[3072+j];
    #pragma unroll
    for (int ds=0; ds<NDS; ++ds){
      size_t base = ((size_t)ds*R_N + r)*4096;
      gi += gpart[base + j];      gf += gpart[base + 1024 + j];
      gg += gpart[base + 2048+j]; go += gpart[base + 3072 + j];
    }
    float cv = c[(size_t)r*H_N + j];
    float c2 = sigmf(gf)*cv + sigmf(gi)*tanhf(gg);
    float h2 = sigmf(go)*tanhf(c2);
    c[(size_t)r*H_N + j] = c2;
    xn[(size_t)r*D2 + DIN + j] = h2;
    h2t[(size_t)j*R_N + r] = h2;
  }
}

// ---- logits GEMM, K-split x4, 8x8 thread tile (pattern-B cols) -> plog[4][64][32000]
// grid (125, 4) x 256 thr. Block: 256 cols x 64 rows x 256 dd.
// Thread cols: {cg*4..+3} and {128+cg*4..+3} -> every LDS read and global store
// is 32 lanes x contiguous 16B (conflict-free, full-line writes).
__global__ __launch_bounds__(256) void k_logits_split(
    const float* __restrict__ h2t, const float* __restrict__ w_out,
    float* __restrict__ plog){
  int tid = threadIdx.x;
  int cg = tid & 31;          // col quad: cols cb+cg*4..+3 and cb+128+cg*4..+3
  int rg = tid >> 5;          // row group: rows rg*8 .. +7
  int cb = blockIdx.x * 256;
  int ks = blockIdx.y;
  int srow = tid >> 4, scol = tid & 15;   // staging: 16 dd-rows x 16 segs

  __shared__ float Wt0[16][256], Wt1[16][256];
  __shared__ float Ht0[16][64],  Ht1[16][64];

  float acc[8][8];
  #pragma unroll
  for (int cc=0;cc<8;++cc)
    #pragma unroll
    for (int rr=0;rr<8;++rr) acc[cc][rr]=0.f;

  const float* gW = w_out + (size_t)(ks*256 + srow)*V_N + cb + scol*16;
  const float* gH = h2t + (size_t)(ks*256 + srow)*64 + scol*4;

#define LLQ(WR, HR, ch) { \
  const float* gWn = gW + (size_t)(ch)*16*V_N; \
  const float* gHn = gH + (size_t)(ch)*16*64; \
  WR[0]=*(const float4*)(gWn);   WR[1]=*(const float4*)(gWn+4); \
  WR[2]=*(const float4*)(gWn+8); WR[3]=*(const float4*)(gWn+12); \
  HR = *(const float4*)(gHn); }
#define LSQ(Wt, Ht, WR, HR) { \
  *(float4*)&Wt[srow][scol*16+ 0] = WR[0]; \
  *(float4*)&Wt[srow][scol*16+ 4] = WR[1]; \
  *(float4*)&Wt[srow][scol*16+ 8] = WR[2]; \
  *(float4*)&Wt[srow][scol*16+12] = WR[3]; \
  *(float4*)&Ht[srow][scol*4]     = HR; }
#define LCQ(Wt, Ht) { _Pragma("unroll 4") for (int dd=0; dd<16; ++dd){ \
    float4 wa = *(const float4*)&Wt[dd][cg*4]; \
    float4 wb = *(const float4*)&Wt[dd][128 + cg*4]; \
    float4 ha = *(const float4*)&Ht[dd][rg*8]; \
    float4 hb = *(const float4*)&Ht[dd][rg*8+4]; \
    FMA4x4(wa,ha,0,0) FMA4x4(wa,hb,0,4) FMA4x4(wb,ha,4,0) FMA4x4(wb,hb,4,4) } }

  float4 w0[4], w1[4], h0, h1;
  LLQ(w0, h0, 0)
  LSQ(Wt0, Ht0, w0, h0)
  LLQ(w1, h1, 1)
  __syncthreads();

  for (int ch=0; ch<16; ch+=2){
    if (ch+2<16) LLQ(w0, h0, ch+2)
    LSQ(Wt1, Ht1, w1, h1)
    LCQ(Wt0, Ht0)
    __syncthreads();
    if (ch+3<16) LLQ(w1, h1, ch+3)
    if (ch+2<16) LSQ(Wt0, Ht0, w0, h0)
    LCQ(Wt1, Ht1)
    if (ch+2<16) __syncthreads();
  }

  #pragma unroll
  for (int rr=0;rr<8;++rr){
    int row = rg*8 + rr;
    float4 o1, o2;
    o1.x=acc[0][rr]; o1.y=acc[1][rr]; o1.z=acc[2][rr]; o1.w=acc[3][rr];
    o2.x=acc[4][rr]; o2.y=acc[5][rr]; o2.z=acc[6][rr]; o2.w=acc[7][rr];
    float* base = &plog[((size_t)ks*R_N + row)*V_N + cb];
    *(float4*)(base + cg*4)       = o1;   // lanes contiguous: full-line stores
    *(float4*)(base + 128 + cg*4) = o2;
  }
}

// ---- stats: sum the four K-slices + bias, per-row softmax stats & top-4.
// 500 blocks x 256 thr; 64-col tiles; width-16 butterfly.
__global__ __launch_bounds__(256) void k_stats(
    const float* __restrict__ plog, const float* __restrict__ b_out,
    float* __restrict__ pm, float* __restrict__ pz,
    float* __restrict__ pv, int* __restrict__ pi){
  int tid = threadIdx.x;
  int cx = tid & 15, ry = tid >> 4;
  int cb = blockIdx.x * 64;
  float4 bias = *(const float4*)&b_out[cb + cx*4];
  #pragma unroll
  for (int rr=0;rr<4;++rr){
    int row = ry*4 + rr;
    float4 a0 = *(const float4*)&plog[((size_t)0*R_N+row)*V_N + cb + cx*4];
    float4 a1 = *(const float4*)&plog[((size_t)1*R_N+row)*V_N + cb + cx*4];
    float4 a2 = *(const float4*)&plog[((size_t)2*R_N+row)*V_N + cb + cx*4];
    float4 a3 = *(const float4*)&plog[((size_t)3*R_N+row)*V_N + cb + cx*4];
    float v0 = a0.x+a1.x+a2.x+a3.x+bias.x;
    float v1 = a0.y+a1.y+a2.y+a3.y+bias.y;
    float v2 = a0.z+a1.z+a2.z+a3.z+bias.z;
    float v3 = a0.w+a1.w+a2.w+a3.w+bias.w;
    int   c0i = cb + cx*4;
    float tv0=-INFINITY,tv1=-INFINITY,tv2=-INFINITY,tv3=-INFINITY;
    int   ti0=0x7fffffff,ti1=0x7fffffff,ti2=0x7fffffff,ti3=0x7fffffff;
    ins4(v0,c0i+0,tv0,tv1,tv2,tv3,ti0,ti1,ti2,ti3);
    ins4(v1,c0i+1,tv0,tv1,tv2,tv3,ti0,ti1,ti2,ti3);
    ins4(v2,c0i+2,tv0,tv1,tv2,tv3,ti0,ti1,ti2,ti3);
    ins4(v3,c0i+3,tv0,tv1,tv2,tv3,ti0,ti1,ti2,ti3);
    float z = expf(v0-tv0)+expf(v1-tv0)+expf(v2-tv0)+expf(v3-tv0);
    #pragma unroll
    for (int msk=1; msk<16; msk<<=1){
      float om  = __shfl_xor(tv0, msk, 16);
      float oz  = __shfl_xor(z,   msk, 16);
      float ov1 = __shfl_xor(tv1, msk, 16);
      float ov2 = __shfl_xor(tv2, msk, 16);
      float ov3 = __shfl_xor(tv3, msk, 16);
      int   oi0 = __shfl_xor(ti0, msk, 16);
      int   oi1 = __shfl_xor(ti1, msk, 16);
      int   oi2 = __shfl_xor(ti2, msk, 16);
      int   oi3 = __shfl_xor(ti3, msk, 16);
      float M = fmaxf(tv0, om);
      z = z*expf(tv0-M) + oz*expf(om-M);
      ins4(om, oi0, tv0,tv1,tv2,tv3, ti0,ti1,ti2,ti3);
      ins4(ov1,oi1, tv0,tv1,tv2,tv3, ti0,ti1,ti2,ti3);
      ins4(ov2,oi2, tv0,tv1,tv2,tv3, ti0,ti1,ti2,ti3);
      ins4(ov3,oi3, tv0,tv1,tv2,tv3, ti0,ti1,ti2,ti3);
    }
    if (cx == 0){
      size_t base = (size_t)row*NB + blockIdx.x;   // [row][block]
      pm[base]=tv0; pz[base]=z;
      pv[base*4+0]=tv0; pv[base*4+1]=tv1; pv[base*4+2]=tv2; pv[base*4+3]=tv3;
      pi[base*4+0]=ti0; pi[base*4+1]=ti1; pi[base*4+2]=ti2; pi[base*4+3]=ti3;
    }
  }
}

// ---- fallback: fused logits+stats (round-6 kernel), used if ws too small.
__global__ __launch_bounds__(256) void k_logits_fused(
    const float* __restrict__ h2t, const float* __restrict__ w_out,
    const float* __restrict__ b_out,
    float* __restrict__ pm, float* __restrict__ pz,
    float* __restrict__ pv, int* __restrict__ pi){
  int tid = threadIdx.x;
  int cx  = tid & 15, ry = tid >> 4;
  int cb  = blockIdx.x * 64;
  int sdd = tid >> 4, seg = tid & 15;
  __shared__ float Wt[32][64];
  __shared__ float Ht[32][64];
  float acc[4][4];
  #pragma unroll
  for (int cc=0;cc<4;++cc)
    #pragma unroll
    for (int rr=0;rr<4;++rr) acc[cc][rr]=0.f;
  const float* gW = w_out + (size_t)sdd*V_N + cb + seg*4;
  const float* gH = h2t + sdd*64 + seg*4;
#define FLQ(WA,WB,HA,HB, ch) { \
  const float* gWn = gW + (size_t)(ch)*32*V_N; \
  const float* gHn = gH + (size_t)(ch)*32*64; \
  WA = *(const float4*)gWn; WB = *(const float4*)(gWn + (size_t)16*V_N); \
  HA = *(const float4*)gHn; HB = *(const float4*)(gHn + 16*64); }
#define FSQ(WA,WB,HA,HB) { \
  *(float4*)&Wt[sdd][seg*4]    = WA; \
  *(float4*)&Wt[sdd+16][seg*4] = WB; \
  *(float4*)&Ht[sdd][seg*4]    = HA; \
  *(float4*)&Ht[sdd+16][seg*4] = HB; }
#define FCQ() { _Pragma("unroll 8") for (int dd=0; dd<32; ++dd){ \
    float4 w4 = *(const float4*)&Wt[dd][cx*4]; \
    float4 h4 = *(const float4*)&Ht[dd][ry*4]; \
    FMA16(w4, h4) } }
  float4 wA0,wB0,hA0,hB0, wA1,wB1,hA1,hB1;
  FLQ(wA0,wB0,hA0,hB0, 0)
  FSQ(wA0,wB0,hA0,hB0)
  FLQ(wA1,wB1,hA1,hB1, 1)
  __syncthreads();
  for (int ch=0; ch<32; ch+=2){
    if (ch+2<32) FLQ(wA0,wB0,hA0,hB0, ch+2)
    FCQ()
    __syncthreads();
    FSQ(wA1,wB1,hA1,hB1)
    __syncthreads();
    if (ch+3<32) FLQ(wA1,wB1,hA1,hB1, ch+3)
    FCQ()
    if (ch+2<32){
      __syncthreads();
      FSQ(wA0,wB0,hA0,hB0)
      __syncthreads();
    }
  }
  float4 bias = *(const float4*)&b_out[cb + cx*4];
  #pragma unroll
  for (int rr=0;rr<4;++rr){
    float v0 = acc[0][rr]+bias.x, v1 = acc[1][rr]+bias.y;
    float v2 = acc[2][rr]+bias.z, v3 = acc[3][rr]+bias.w;
    int   c0i = cb + cx*4;
    float tv0=-INFINITY,tv1=-INFINITY,tv2=-INFINITY,tv3=-INFINITY;
    int   ti0=0x7fffffff,ti1=0x7fffffff,ti2=0x7fffffff,ti3=0x7fffffff;
    ins4(v0,c0i+0,tv0,tv1,tv2,tv3,ti0,ti1,ti2,ti3);
    ins4(v1,c0i+1,tv0,tv1,tv2,tv3,ti0,ti1,ti2,ti3);
    ins4(v2,c0i+2,tv0,tv1,tv2,tv3,ti0,ti1,ti2,ti3);
    ins4(v3,c0i+3,tv0,tv1,tv2,tv3,ti0,ti1,ti2,ti3);
    float z = expf(v0-tv0)+expf(v1-tv0)+expf(v2-tv0)+expf(v3-tv0);
    #pragma unroll
    for (int msk=1; msk<16; msk<<=1){
      float om  = __shfl_xor(tv0, msk, 16);
      float oz  = __shfl_xor(z,   msk, 16);
      float ov1 = __shfl_xor(tv1, msk, 16);
      float ov2 = __shfl_xor(tv2, msk, 16);
      float ov3 = __shfl_xor(tv3, msk, 16);
      int   oi0 = __shfl_xor(ti0, msk, 16);
      int   oi1 = __shfl_xor(ti1, msk, 16);
      int   oi2 = __shfl_xor(ti2, msk, 16);
      int   oi3 = __shfl_xor(ti3, msk, 16);
      float M = fmaxf(tv0, om);
      z = z*expf(tv0-M) + oz*expf(om-M);
      ins4(om, oi0, tv0,tv1,tv2,tv3, ti0,ti1,ti2,ti3);
      ins4(ov1,oi1, tv0,tv1,tv2,tv3, ti0,ti1,ti2,ti3);
      ins4(ov2,oi2, tv0,tv1,tv2,tv3, ti0,ti1,ti2,ti3);
      ins4(ov3,oi3, tv0,tv1,tv2,tv3, ti0,ti1,ti2,ti3);
    }
    if (cx == 0){
      int row = ry*4 + rr;
      size_t base = (size_t)row*NB + blockIdx.x;
      pm[base]=tv0; pz[base]=z;
      pv[base*4+0]=tv0; pv[base*4+1]=tv1; pv[base*4+2]=tv2; pv[base*4+3]=tv3;
      pi[base*4+0]=ti0; pi[base*4+1]=ti1; pi[base*4+2]=ti2; pi[base*4+3]=ti3;
    }
  }
}

// ---- final: reduce NB partials per row, joint top-4 per b, write out, next-x.
__global__ __launch_bounds__(256) void k_final(
    const float* __restrict__ pm, const float* __restrict__ pz,
    const float* __restrict__ pv, const int* __restrict__ pi,
    float* __restrict__ scores, int* __restrict__ out, int t,
    float* __restrict__ xn,
    const float* __restrict__ enc_inputs, const float* __restrict__ enc_outputs,
    const float* __restrict__ embed){
  int b = blockIdx.x, tid = threadIdx.x;
  __shared__ float sm[256], sz[256], stv[1024];
  __shared__ int   sti[1024];
  __shared__ float fM[KBEAM], fZ[KBEAM], fV[16];
  __shared__ int   fI[16], sw[KBEAM];
  int nk = (t==0) ? 1 : KBEAM;
  for (int k=0;k<nk;++k){
    size_t rb = (size_t)(k*B_N + b)*NB;
    float m=-INFINITY, z=0.f;
    float av0=-INFINITY,av1=-INFINITY,av2=-INFINITY,av3=-INFINITY;
    int   ai0=0x7fffffff,ai1=0x7fffffff,ai2=0x7fffffff,ai3=0x7fffffff;
    for (int p0=tid; p0<NB; p0+=256){
      size_t p = rb + p0;
      float mf = pm[p];
      float M = fmaxf(m, mf);
      z = z*expf(m-M) + pz[p]*expf(mf-M);
      m = M;
      #pragma unroll
      for (int q=0;q<4;++q)
        ins4(pv[p*4+q], pi[p*4+q], av0,av1,av2,av3, ai0,ai1,ai2,ai3);
    }
    sm[tid]=m; sz[tid]=z;
    stv[tid*4+0]=av0; stv[tid*4+1]=av1; stv[tid*4+2]=av2; stv[tid*4+3]=av3;
    sti[tid*4+0]=ai0; sti[tid*4+1]=ai1; sti[tid*4+2]=ai2; sti[tid*4+3]=ai3;
    __syncthreads();
    for (int off=128; off>0; off>>=1){
      if (tid<off){
        float ma=sm[tid], mb=sm[tid+off];
        float za=sz[tid], zb=sz[tid+off];
        float M = fmaxf(ma,mb);
        sz[tid] = za*expf(ma-M) + zb*expf(mb-M);
        sm[tid] = M;
        float bv0=stv[tid*4],bv1=stv[tid*4+1],bv2=stv[tid*4+2],bv3=stv[tid*4+3];
        int   bi0=sti[tid*4],bi1=sti[tid*4+1],bi2=sti[tid*4+2],bi3=sti[tid*4+3];
        #pragma unroll
        for (int q=0;q<4;++q)
          ins4(stv[(tid+off)*4+q], sti[(tid+off)*4+q],
               bv0,bv1,bv2,bv3, bi0,bi1,bi2,bi3);
        stv[tid*4]=bv0; stv[tid*4+1]=bv1; stv[tid*4+2]=bv2; stv[tid*4+3]=bv3;
        sti[tid*4]=bi0; sti[tid*4+1]=bi1; sti[tid*4+2]=bi2; sti[tid*4+3]=bi3;
      }
      __syncthreads();
    }
    if (tid==0){
      fM[k]=sm[0]; fZ[k]=sz[0];
      fV[k*4+0]=stv[0]; fV[k*4+1]=stv[1]; fV[k*4+2]=stv[2]; fV[k*4+3]=stv[3];
      fI[k*4+0]=sti[0]; fI[k*4+1]=sti[1]; fI[k*4+2]=sti[2]; fI[k*4+3]=sti[3];
    }
    __syncthreads();
  }
  if (tid==0){
    if (t==0){
      #pragma unroll
      for (int j=0;j<4;++j){
        float p = expf(fV[j]-fM[0])/fZ[0];
        scores[b*4+j] = p;
        out[j*(B_N*S_LEN) + b*S_LEN] = fI[j];
        sw[j] = fI[j];
      }
    } else {
      float cv[16]; int cj[16];
      for (int k=0;k<4;++k){
        float s = scores[b*4+k];
        #pragma unroll
        for (int j=0;j<4;++j){
          cv[k*4+j] = expf(fV[k*4+j]-fM[k])/fZ[k]*s;
          cj[k*4+j] = k*V_N + fI[k*4+j];
        }
      }
      bool used[16];
      for (int i=0;i<16;++i) used[i]=false;
      for (int rank=0;rank<4;++rank){
        int best=-1;
        for (int i=0;i<16;++i){
          if (used[i]) continue;
          if (best<0 || cv[i]>cv[best] || (cv[i]==cv[best] && cj[i]<cj[best])) best=i;
        }
        used[best]=true;
        out[rank*(B_N*S_LEN) + b*S_LEN + t] = cj[best];
        sw[rank] = cj[best] % V_N;
      }
    }
  }
  __syncthreads();
  if (t < S_LEN-1){
    const float* ein = enc_inputs  + (size_t)(t+1)*B_N*E_N + (size_t)b*E_N;
    const float* eo  = enc_outputs + (size_t)(t+1)*B_N*H_N + (size_t)b*H_N;
    #pragma unroll
    for (int j=0;j<KBEAM;++j){
      float* xr = xn + (size_t)(j*B_N + b)*D2;
      const float* em = embed + (size_t)sw[j]*E_N;
      xr[tid]       = em[tid];
      xr[E_N + tid] = ein[tid];
      #pragma unroll
      for (int q=0;q<4;++q) xr[2*E_N + q*256 + tid] = eo[q*256 + tid];
    }
  }
}

extern "C" void kernel_launch(void* const* d_in, const int* in_sizes, int n_in,
                              void* d_out, int out_size, void* d_ws, size_t ws_size,
                              hipStream_t stream) {
  (void)in_sizes; (void)n_in; (void)out_size;
  const float* enc_h_n     = (const float*)d_in[0];
  const float* enc_c_n     = (const float*)d_in[1];
  const float* enc_outputs = (const float*)d_in[2];
  const float* enc_inputs  = (const float*)d_in[3];
  const float* embed       = (const float*)d_in[4];
  const float* w_ih        = (const float*)d_in[5];
  const float* w_hh        = (const float*)d_in[6];
  const float* b_lstm      = (const float*)d_in[7];
  const float* w_out       = (const float*)d_in[8];
  const float* b_out       = (const float*)d_in[9];
  int* out = (int*)d_out;

  float* ws = (float*)d_ws;
  const size_t FRONTF = (size_t)R_N*D2*2 + (size_t)R_N*H_N + (size_t)H_N*R_N; // 458752
  const size_t PLOGF  = (size_t)LKS*R_N*V_N;    // 8,192,000
  const size_t GPARTF = (size_t)NDS*R_N*4096;   // 2,097,152
  const size_t STATF  = (size_t)R_N*NB*10;      // 320,000
  size_t need_split = (FRONTF + PLOGF + STATF + 64)*sizeof(float);
  bool use_split = (ws_size >= need_split);

  float* xA     = ws;
  float* xB     = xA + (size_t)R_N*D2;
  float* cbuf   = xB + (size_t)R_N*D2;
  float* h2t    = cbuf + (size_t)R_N*H_N;
  float* big    = h2t + (size_t)H_N*R_N;
  float* gpart  = big;                       // lifetime: k_gates -> k_lstm
  float* plog   = big;                       // lifetime: k_logits_split -> k_stats
  float *pm, *pz, *pv, *scoresb; int *pi;
  if (use_split){
    pm = big + PLOGF;
    pz = pm + (size_t)R_N*NB;
    pv = pz + (size_t)R_N*NB;
    pi = (int*)(pv + (size_t)R_N*NB*4);
    scoresb = (float*)(pi + (size_t)R_N*NB*4);
  } else {
    pm = big;                                // aliased inside gpart (disjoint lifetime)
    pz = pm + (size_t)R_N*NB;
    pv = pz + (size_t)R_N*NB;
    pi = (int*)(pv + (size_t)R_N*NB*4);
    scoresb = big + GPARTF;
  }

  k_init<<<R_N, 256, 0, stream>>>(enc_h_n, enc_c_n, enc_outputs, enc_inputs, embed, xA, cbuf);

  for (int t=0; t<S_LEN; ++t){
    float* xc = (t & 1) ? xB : xA;
    float* xn = (t & 1) ? xA : xB;
    k_gates <<<dim3(64, NDS), 256, 0, stream>>>(xc, w_ih, w_hh, gpart);
    k_lstm  <<<R_N, 256, 0, stream>>>(gpart, b_lstm, cbuf, xn, h2t);
    if (use_split){
      k_logits_split<<<dim3(LCB, LKS), 256, 0, stream>>>(h2t, w_out, plog);
      k_stats<<<NB, 256, 0, stream>>>(plog, b_out, pm, pz, pv, pi);
    } else {
      k_logits_fused<<<NB, 256, 0, stream>>>(h2t, w_out, b_out, pm, pz, pv, pi);
    }
    k_final <<<B_N, 256, 0, stream>>>(pm, pz, pv, pi, scoresb, out, t, xn,
                                      enc_inputs, enc_outputs, embed);
  }
}

// Round 10
// 4977.354 us; speedup vs baseline: 1.0436x; 1.0352x over previous
//
#include <hip/hip_runtime.h>
#include <math.h>

#define S_LEN 32
#define B_N   16
#define H_N   1024
#define E_N   256
#define V_N   32000
#define KBEAM 4
#define DIN   1536
#define D2    2560   // DIN + H_N
#define R_N   64     // KBEAM * B_N rows of state
#define NDS   8      // K-slices for gates GEMM (320 each)
#define NB    500    // stats col-blocks = V_N/64
#define LKS   4      // logits K-split
#define LCB   250    // logits col-blocks = V_N/128

__device__ __forceinline__ float sigmf(float x){ return 1.0f/(1.0f+expf(-x)); }
__device__ __forceinline__ bool better(float v1,int i1,float v2,int i2){
  return (v1>v2) || (v1==v2 && i1<i2);
}
// insert candidate (bv,bi) into sorted-desc top-4 (av0 best)
__device__ __forceinline__ void ins4(float bv,int bi,
    float&av0,float&av1,float&av2,float&av3,int&ai0,int&ai1,int&ai2,int&ai3){
  if (better(bv,bi,av3,ai3)){ av3=bv; ai3=bi;
    if (better(av3,ai3,av2,ai2)){ float t=av2;av2=av3;av3=t; int q=ai2;ai2=ai3;ai3=q;
      if (better(av2,ai2,av1,ai1)){ t=av1;av1=av2;av2=t; q=ai1;ai1=ai2;ai2=q;
        if (better(av1,ai1,av0,ai0)){ t=av0;av0=av1;av1=t; q=ai0;ai0=ai1;ai1=q; } } } }
}

// 4x4 FMA micro-tile into acc[4][4]
#define FMA16(w4, h4) { \
  acc[0][0]=fmaf(w4.x,h4.x,acc[0][0]); acc[0][1]=fmaf(w4.x,h4.y,acc[0][1]); \
  acc[0][2]=fmaf(w4.x,h4.z,acc[0][2]); acc[0][3]=fmaf(w4.x,h4.w,acc[0][3]); \
  acc[1][0]=fmaf(w4.y,h4.x,acc[1][0]); acc[1][1]=fmaf(w4.y,h4.y,acc[1][1]); \
  acc[1][2]=fmaf(w4.y,h4.z,acc[1][2]); acc[1][3]=fmaf(w4.y,h4.w,acc[1][3]); \
  acc[2][0]=fmaf(w4.z,h4.x,acc[2][0]); acc[2][1]=fmaf(w4.z,h4.y,acc[2][1]); \
  acc[2][2]=fmaf(w4.z,h4.z,acc[2][2]); acc[2][3]=fmaf(w4.z,h4.w,acc[2][3]); \
  acc[3][0]=fmaf(w4.w,h4.x,acc[3][0]); acc[3][1]=fmaf(w4.w,h4.y,acc[3][1]); \
  acc[3][2]=fmaf(w4.w,h4.z,acc[3][2]); acc[3][3]=fmaf(w4.w,h4.w,acc[3][3]); }

// 4x4 FMA micro-tile into acc[CO..CO+3][0..3]
#define FMA4x4(w4, h4, CO) { \
  acc[CO+0][0]=fmaf(w4.x,h4.x,acc[CO+0][0]); acc[CO+0][1]=fmaf(w4.x,h4.y,acc[CO+0][1]); \
  acc[CO+0][2]=fmaf(w4.x,h4.z,acc[CO+0][2]); acc[CO+0][3]=fmaf(w4.x,h4.w,acc[CO+0][3]); \
  acc[CO+1][0]=fmaf(w4.y,h4.x,acc[CO+1][0]); acc[CO+1][1]=fmaf(w4.y,h4.y,acc[CO+1][1]); \
  acc[CO+1][2]=fmaf(w4.y,h4.z,acc[CO+1][2]); acc[CO+1][3]=fmaf(w4.y,h4.w,acc[CO+1][3]); \
  acc[CO+2][0]=fmaf(w4.z,h4.x,acc[CO+2][0]); acc[CO+2][1]=fmaf(w4.z,h4.y,acc[CO+2][1]); \
  acc[CO+2][2]=fmaf(w4.z,h4.z,acc[CO+2][2]); acc[CO+2][3]=fmaf(w4.z,h4.w,acc[CO+2][3]); \
  acc[CO+3][0]=fmaf(w4.w,h4.x,acc[CO+3][0]); acc[CO+3][1]=fmaf(w4.w,h4.y,acc[CO+3][1]); \
  acc[CO+3][2]=fmaf(w4.w,h4.z,acc[CO+3][2]); acc[CO+3][3]=fmaf(w4.w,h4.w,acc[CO+3][3]); }

// ---- init: x0 = [embed[START] | enc_inputs[0] | enc_outputs[0]] , c0
__global__ __launch_bounds__(256) void k_init(
    const float* __restrict__ enc_h_n, const float* __restrict__ enc_c_n,
    const float* __restrict__ enc_outputs, const float* __restrict__ enc_inputs,
    const float* __restrict__ embed, float* __restrict__ x, float* __restrict__ c){
  int r = blockIdx.x, tid = threadIdx.x, b = r & 15;
  float* xr = x + (size_t)r*D2;
  xr[tid]        = embed[E_N + tid];                 // START token = 1
  xr[E_N + tid]  = enc_inputs[b*E_N + tid];          // t = 0
  #pragma unroll
  for (int q=0;q<4;++q) xr[2*E_N + q*256 + tid] = enc_outputs[b*H_N + q*256 + tid];
  #pragma unroll
  for (int q=0;q<4;++q) xr[DIN + q*256 + tid]   = enc_h_n[b*H_N + q*256 + tid];
  #pragma unroll
  for (int q=0;q<4;++q) c[(size_t)r*H_N + q*256 + tid] = enc_c_n[b*H_N + q*256 + tid];
}

// ---- gates GEMM (LDS double-buffered, 1 barrier/chunk): gpart[ks][64][4096]
// grid (64 col-tiles x 8 K-slices), 256 thr. Block: 64 cols x 64 rows, K=320.
#define GWLD(d, off) (*(const float4*)((((d) < DIN) ? (w_ih + (size_t)(d)*4096) \
                       : (w_hh + (size_t)((d)-DIN)*4096)) + (off)))
__global__ __launch_bounds__(256) void k_gates(
    const float* __restrict__ x, const float* __restrict__ w_ih,
    const float* __restrict__ w_hh, float* __restrict__ gpart){
  int tid = threadIdx.x;
  int jt = blockIdx.x, ks = blockIdx.y;
  int cx = tid & 15, ry = tid >> 4;
  int cb = jt*64;
  int wdd = tid >> 4, wseg = tid & 15;   // W stage: 16 dd x 16 col-segs (x2)
  int xrow = tid >> 3, xseg = tid & 7;   // X stage: 32 rows x 8 dd-segs (x2)

  __shared__ float Wt0[32][64], Wt1[32][64];
  __shared__ float Xt0[32][68], Xt1[32][68];

  float acc[4][4];
  #pragma unroll
  for (int cc=0;cc<4;++cc)
    #pragma unroll
    for (int rr=0;rr<4;++rr) acc[cc][rr]=0.f;

  int d0 = ks*320;                       // NCH = 10 chunks of 32
  const float* xp0 = x + (size_t)xrow*D2 + d0 + xseg*4;
  const float* xp1 = x + (size_t)(xrow+32)*D2 + d0 + xseg*4;

#define GLQ(WA,WB,X0,X1, ch) { int d_ = d0 + (ch)*32; \
  WA = GWLD(d_+wdd,    cb+wseg*4); \
  WB = GWLD(d_+16+wdd, cb+wseg*4); \
  X0 = *(const float4*)(xp0 + (ch)*32); \
  X1 = *(const float4*)(xp1 + (ch)*32); }
#define GSQ(Wt,Xt, WA,WB,X0,X1) { \
  *(float4*)&Wt[wdd][wseg*4]    = WA; \
  *(float4*)&Wt[wdd+16][wseg*4] = WB; \
  Xt[xseg*4+0][xrow] = X0.x; Xt[xseg*4+1][xrow] = X0.y; \
  Xt[xseg*4+2][xrow] = X0.z; Xt[xseg*4+3][xrow] = X0.w; \
  Xt[xseg*4+0][xrow+32] = X1.x; Xt[xseg*4+1][xrow+32] = X1.y; \
  Xt[xseg*4+2][xrow+32] = X1.z; Xt[xseg*4+3][xrow+32] = X1.w; }
#define GCQ(Wt,Xt) { _Pragma("unroll 8") for (int dd=0; dd<32; ++dd){ \
    float4 w4 = *(const float4*)&Wt[dd][cx*4]; \
    float4 h4 = *(const float4*)&Xt[dd][ry*4]; \
    FMA16(w4, h4) } }

  float4 wA0,wB0,x00,x10, wA1,wB1,x01,x11;
  GLQ(wA0,wB0,x00,x10, 0)
  GSQ(Wt0,Xt0, wA0,wB0,x00,x10)
  GLQ(wA1,wB1,x01,x11, 1)
  __syncthreads();

  for (int ch=0; ch<10; ch+=2){
    if (ch+2<10) GLQ(wA0,wB0,x00,x10, ch+2)
    GSQ(Wt1,Xt1, wA1,wB1,x01,x11)
    GCQ(Wt0,Xt0)
    __syncthreads();
    if (ch+3<10) GLQ(wA1,wB1,x01,x11, ch+3)
    if (ch+2<10) GSQ(Wt0,Xt0, wA0,wB0,x00,x10)
    GCQ(Wt1,Xt1)
    if (ch+2<10) __syncthreads();
  }
  #pragma unroll
  for (int rr=0;rr<4;++rr){
    float4 o; o.x=acc[0][rr]; o.y=acc[1][rr]; o.z=acc[2][rr]; o.w=acc[3][rr];
    *(float4*)&gpart[((size_t)(ks*R_N + ry*4+rr))*4096 + cb + cx*4] = o;
  }
}

// ---- LSTM: sum partials + bias, cell update; h2 -> xn[.,1536:] and h2t[1024][64]
__global__ __launch_bounds__(256) void k_lstm(
    const float* __restrict__ gpart, const float* __restrict__ b_lstm,
    float* __restrict__ c, float* __restrict__ xn, float* __restrict__ h2t){
  int r = blockIdx.x, tid = threadIdx.x;
  #pragma unroll
  for (int it=0; it<4; ++it){
    int j = it*256 + tid;
    float gi = b_lstm[j], gf = b_lstm[1024+j], gg = b_lstm[2048+j], go = b_lstm[3072+j];
    #pragma unroll
    for (int ds=0; ds<NDS; ++ds){
      size_t base = ((size_t)ds*R_N + r)*4096;
      gi += gpart[base + j];      gf += gpart[base + 1024 + j];
      gg += gpart[base + 2048+j]; go += gpart[base + 3072 + j];
    }
    float cv = c[(size_t)r*H_N + j];
    float c2 = sigmf(gf)*cv + sigmf(gi)*tanhf(gg);
    float h2 = sigmf(go)*tanhf(c2);
    c[(size_t)r*H_N + j] = c2;
    xn[(size_t)r*D2 + DIN + j] = h2;
    h2t[(size_t)j*R_N + r] = h2;
  }
}

// ---- logits GEMM, K-split x4, 8x4 thread tile (pattern-B cols, no spill)
// grid (250, 4) x 256 thr. Block: 128 cols x 64 rows x 256 dd.
// Thread: cols {cg*4..+3, 64+cg*4..+3}, rows rg*4..+3. acc[8][4]=32 VGPR.
__global__ __launch_bounds__(256) void k_logits_split(
    const float* __restrict__ h2t, const float* __restrict__ w_out,
    float* __restrict__ plog){
  int tid = threadIdx.x;
  int cg = tid & 15;          // col quad within 64-col half
  int rg = tid >> 4;          // row group: rows rg*4 .. +3 (0..15)
  int cb = blockIdx.x * 128;
  int ks = blockIdx.y;
  int srow = tid >> 4, sseg = tid & 15;   // staging: 16 dd-rows x 16 segs

  __shared__ float Wt0[16][128], Wt1[16][128];
  __shared__ float Ht0[16][64],  Ht1[16][64];

  float acc[8][4];
  #pragma unroll
  for (int cc=0;cc<8;++cc)
    #pragma unroll
    for (int rr=0;rr<4;++rr) acc[cc][rr]=0.f;

  const float* gW = w_out + (size_t)(ks*256 + srow)*V_N + cb + sseg*8;
  const float* gH = h2t + (size_t)(ks*256 + srow)*64 + sseg*4;

#define LLQ(WR, HR, ch) { \
  const float* gWn = gW + (size_t)(ch)*16*V_N; \
  const float* gHn = gH + (size_t)(ch)*16*64; \
  WR[0]=*(const float4*)(gWn); WR[1]=*(const float4*)(gWn+4); \
  HR = *(const float4*)(gHn); }
#define LSQ(Wt, Ht, WR, HR) { \
  *(float4*)&Wt[srow][sseg*8]   = WR[0]; \
  *(float4*)&Wt[srow][sseg*8+4] = WR[1]; \
  *(float4*)&Ht[srow][sseg*4]   = HR; }
#define LCQ(Wt, Ht) { _Pragma("unroll 4") for (int dd=0; dd<16; ++dd){ \
    float4 wa = *(const float4*)&Wt[dd][cg*4]; \
    float4 wb = *(const float4*)&Wt[dd][64 + cg*4]; \
    float4 ha = *(const float4*)&Ht[dd][rg*4]; \
    FMA4x4(wa,ha,0) FMA4x4(wb,ha,4) } }

  float4 w0[2], w1[2], h0, h1;
  LLQ(w0, h0, 0)
  LSQ(Wt0, Ht0, w0, h0)
  LLQ(w1, h1, 1)
  __syncthreads();

  for (int ch=0; ch<16; ch+=2){
    if (ch+2<16) LLQ(w0, h0, ch+2)
    LSQ(Wt1, Ht1, w1, h1)
    LCQ(Wt0, Ht0)
    __syncthreads();
    if (ch+3<16) LLQ(w1, h1, ch+3)
    if (ch+2<16) LSQ(Wt0, Ht0, w0, h0)
    LCQ(Wt1, Ht1)
    if (ch+2<16) __syncthreads();
  }

  #pragma unroll
  for (int rr=0;rr<4;++rr){
    int row = rg*4 + rr;
    float4 o1, o2;
    o1.x=acc[0][rr]; o1.y=acc[1][rr]; o1.z=acc[2][rr]; o1.w=acc[3][rr];
    o2.x=acc[4][rr]; o2.y=acc[5][rr]; o2.z=acc[6][rr]; o2.w=acc[7][rr];
    float* base = &plog[((size_t)ks*R_N + row)*V_N + cb];
    *(float4*)(base + cg*4)      = o1;   // 16 lanes x contiguous 16B
    *(float4*)(base + 64 + cg*4) = o2;
  }
}

// ---- stats: sum the four K-slices + bias, per-row softmax stats & top-4.
// 500 blocks x 256 thr; 64-col tiles; width-16 butterfly.
__global__ __launch_bounds__(256) void k_stats(
    const float* __restrict__ plog, const float* __restrict__ b_out,
    float* __restrict__ pm, float* __restrict__ pz,
    float* __restrict__ pv, int* __restrict__ pi){
  int tid = threadIdx.x;
  int cx = tid & 15, ry = tid >> 4;
  int cb = blockIdx.x * 64;
  float4 bias = *(const float4*)&b_out[cb + cx*4];
  #pragma unroll
  for (int rr=0;rr<4;++rr){
    int row = ry*4 + rr;
    float4 a0 = *(const float4*)&plog[((size_t)0*R_N+row)*V_N + cb + cx*4];
    float4 a1 = *(const float4*)&plog[((size_t)1*R_N+row)*V_N + cb + cx*4];
    float4 a2 = *(const float4*)&plog[((size_t)2*R_N+row)*V_N + cb + cx*4];
    float4 a3 = *(const float4*)&plog[((size_t)3*R_N+row)*V_N + cb + cx*4];
    float v0 = a0.x+a1.x+a2.x+a3.x+bias.x;
    float v1 = a0.y+a1.y+a2.y+a3.y+bias.y;
    float v2 = a0.z+a1.z+a2.z+a3.z+bias.z;
    float v3 = a0.w+a1.w+a2.w+a3.w+bias.w;
    int   c0i = cb + cx*4;
    float tv0=-INFINITY,tv1=-INFINITY,tv2=-INFINITY,tv3=-INFINITY;
    int   ti0=0x7fffffff,ti1=0x7fffffff,ti2=0x7fffffff,ti3=0x7fffffff;
    ins4(v0,c0i+0,tv0,tv1,tv2,tv3,ti0,ti1,ti2,ti3);
    ins4(v1,c0i+1,tv0,tv1,tv2,tv3,ti0,ti1,ti2,ti3);
    ins4(v2,c0i+2,tv0,tv1,tv2,tv3,ti0,ti1,ti2,ti3);
    ins4(v3,c0i+3,tv0,tv1,tv2,tv3,ti0,ti1,ti2,ti3);
    float z = expf(v0-tv0)+expf(v1-tv0)+expf(v2-tv0)+expf(v3-tv0);
    #pragma unroll
    for (int msk=1; msk<16; msk<<=1){
      float om  = __shfl_xor(tv0, msk, 16);
      float oz  = __shfl_xor(z,   msk, 16);
      float ov1 = __shfl_xor(tv1, msk, 16);
      float ov2 = __shfl_xor(tv2, msk, 16);
      float ov3 = __shfl_xor(tv3, msk, 16);
      int   oi0 = __shfl_xor(ti0, msk, 16);
      int   oi1 = __shfl_xor(ti1, msk, 16);
      int   oi2 = __shfl_xor(ti2, msk, 16);
      int   oi3 = __shfl_xor(ti3, msk, 16);
      float M = fmaxf(tv0, om);
      z = z*expf(tv0-M) + oz*expf(om-M);
      ins4(om, oi0, tv0,tv1,tv2,tv3, ti0,ti1,ti2,ti3);
      ins4(ov1,oi1, tv0,tv1,tv2,tv3, ti0,ti1,ti2,ti3);
      ins4(ov2,oi2, tv0,tv1,tv2,tv3, ti0,ti1,ti2,ti3);
      ins4(ov3,oi3, tv0,tv1,tv2,tv3, ti0,ti1,ti2,ti3);
    }
    if (cx == 0){
      size_t base = (size_t)row*NB + blockIdx.x;   // [row][block]
      pm[base]=tv0; pz[base]=z;
      pv[base*4+0]=tv0; pv[base*4+1]=tv1; pv[base*4+2]=tv2; pv[base*4+3]=tv3;
      pi[base*4+0]=ti0; pi[base*4+1]=ti1; pi[base*4+2]=ti2; pi[base*4+3]=ti3;
    }
  }
}

// ---- fallback: fused logits+stats (round-6 kernel), used if ws too small.
__global__ __launch_bounds__(256) void k_logits_fused(
    const float* __restrict__ h2t, const float* __restrict__ w_out,
    const float* __restrict__ b_out,
    float* __restrict__ pm, float* __restrict__ pz,
    float* __restrict__ pv, int* __restrict__ pi){
  int tid = threadIdx.x;
  int cx  = tid & 15, ry = tid >> 4;
  int cb  = blockIdx.x * 64;
  int sdd = tid >> 4, seg = tid & 15;
  __shared__ float Wt[32][64];
  __shared__ float Ht[32][64];
  float acc[4][4];
  #pragma unroll
  for (int cc=0;cc<4;++cc)
    #pragma unroll
    for (int rr=0;rr<4;++rr) acc[cc][rr]=0.f;
  const float* gW = w_out + (size_t)sdd*V_N + cb + seg*4;
  const float* gH = h2t + sdd*64 + seg*4;
#define FLQ(WA,WB,HA,HB, ch) { \
  const float* gWn = gW + (size_t)(ch)*32*V_N; \
  const float* gHn = gH + (size_t)(ch)*32*64; \
  WA = *(const float4*)gWn; WB = *(const float4*)(gWn + (size_t)16*V_N); \
  HA = *(const float4*)gHn; HB = *(const float4*)(gHn + 16*64); }
#define FSQ(WA,WB,HA,HB) { \
  *(float4*)&Wt[sdd][seg*4]    = WA; \
  *(float4*)&Wt[sdd+16][seg*4] = WB; \
  *(float4*)&Ht[sdd][seg*4]    = HA; \
  *(float4*)&Ht[sdd+16][seg*4] = HB; }
#define FCQ() { _Pragma("unroll 8") for (int dd=0; dd<32; ++dd){ \
    float4 w4 = *(const float4*)&Wt[dd][cx*4]; \
    float4 h4 = *(const float4*)&Ht[dd][ry*4]; \
    FMA16(w4, h4) } }
  float4 wA0,wB0,hA0,hB0, wA1,wB1,hA1,hB1;
  FLQ(wA0,wB0,hA0,hB0, 0)
  FSQ(wA0,wB0,hA0,hB0)
  FLQ(wA1,wB1,hA1,hB1, 1)
  __syncthreads();
  for (int ch=0; ch<32; ch+=2){
    if (ch+2<32) FLQ(wA0,wB0,hA0,hB0, ch+2)
    FCQ()
    __syncthreads();
    FSQ(wA1,wB1,hA1,hB1)
    __syncthreads();
    if (ch+3<32) FLQ(wA1,wB1,hA1,hB1, ch+3)
    FCQ()
    if (ch+2<32){
      __syncthreads();
      FSQ(wA0,wB0,hA0,hB0)
      __syncthreads();
    }
  }
  float4 bias = *(const float4*)&b_out[cb + cx*4];
  #pragma unroll
  for (int rr=0;rr<4;++rr){
    float v0 = acc[0][rr]+bias.x, v1 = acc[1][rr]+bias.y;
    float v2 = acc[2][rr]+bias.z, v3 = acc[3][rr]+bias.w;
    int   c0i = cb + cx*4;
    float tv0=-INFINITY,tv1=-INFINITY,tv2=-INFINITY,tv3=-INFINITY;
    int   ti0=0x7fffffff,ti1=0x7fffffff,ti2=0x7fffffff,ti3=0x7fffffff;
    ins4(v0,c0i+0,tv0,tv1,tv2,tv3,ti0,ti1,ti2,ti3);
    ins4(v1,c0i+1,tv0,tv1,tv2,tv3,ti0,ti1,ti2,ti3);
    ins4(v2,c0i+2,tv0,tv1,tv2,tv3,ti0,ti1,ti2,ti3);
    ins4(v3,c0i+3,tv0,tv1,tv2,tv3,ti0,ti1,ti2,ti3);
    float z = expf(v0-tv0)+expf(v1-tv0)+expf(v2-tv0)+expf(v3-tv0);
    #pragma unroll
    for (int msk=1; msk<16; msk<<=1){
      float om  = __shfl_xor(tv0, msk, 16);
      float oz  = __shfl_xor(z,   msk, 16);
      float ov1 = __shfl_xor(tv1, msk, 16);
      float ov2 = __shfl_xor(tv2, msk, 16);
      float ov3 = __shfl_xor(tv3, msk, 16);
      int   oi0 = __shfl_xor(ti0, msk, 16);
      int   oi1 = __shfl_xor(ti1, msk, 16);
      int   oi2 = __shfl_xor(ti2, msk, 16);
      int   oi3 = __shfl_xor(ti3, msk, 16);
      float M = fmaxf(tv0, om);
      z = z*expf(tv0-M) + oz*expf(om-M);
      ins4(om, oi0, tv0,tv1,tv2,tv3, ti0,ti1,ti2,ti3);
      ins4(ov1,oi1, tv0,tv1,tv2,tv3, ti0,ti1,ti2,ti3);
      ins4(ov2,oi2, tv0,tv1,tv2,tv3, ti0,ti1,ti2,ti3);
      ins4(ov3,oi3, tv0,tv1,tv2,tv3, ti0,ti1,ti2,ti3);
    }
    if (cx == 0){
      int row = ry*4 + rr;
      size_t base = (size_t)row*NB + blockIdx.x;
      pm[base]=tv0; pz[base]=z;
      pv[base*4+0]=tv0; pv[base*4+1]=tv1; pv[base*4+2]=tv2; pv[base*4+3]=tv3;
      pi[base*4+0]=ti0; pi[base*4+1]=ti1; pi[base*4+2]=ti2; pi[base*4+3]=ti3;
    }
  }
}

// ---- final: reduce NB partials per row, joint top-4 per b, write out, next-x.
__global__ __launch_bounds__(256) void k_final(
    const float* __restrict__ pm, const float* __restrict__ pz,
    const float* __restrict__ pv, const int* __restrict__ pi,
    float* __restrict__ scores, int* __restrict__ out, int t,
    float* __restrict__ xn,
    const float* __restrict__ enc_inputs, const float* __restrict__ enc_outputs,
    const float* __restrict__ embed){
  int b = blockIdx.x, tid = threadIdx.x;
  __shared__ float sm[256], sz[256], stv[1024];
  __shared__ int   sti[1024];
  __shared__ float fM[KBEAM], fZ[KBEAM], fV[16];
  __shared__ int   fI[16], sw[KBEAM];
  int nk = (t==0) ? 1 : KBEAM;
  for (int k=0;k<nk;++k){
    size_t rb = (size_t)(k*B_N + b)*NB;
    float m=-INFINITY, z=0.f;
    float av0=-INFINITY,av1=-INFINITY,av2=-INFINITY,av3=-INFINITY;
    int   ai0=0x7fffffff,ai1=0x7fffffff,ai2=0x7fffffff,ai3=0x7fffffff;
    for (int p0=tid; p0<NB; p0+=256){
      size_t p = rb + p0;
      float mf = pm[p];
      float M = fmaxf(m, mf);
      z = z*expf(m-M) + pz[p]*expf(mf-M);
      m = M;
      #pragma unroll
      for (int q=0;q<4;++q)
        ins4(pv[p*4+q], pi[p*4+q], av0,av1,av2,av3, ai0,ai1,ai2,ai3);
    }
    sm[tid]=m; sz[tid]=z;
    stv[tid*4+0]=av0; stv[tid*4+1]=av1; stv[tid*4+2]=av2; stv[tid*4+3]=av3;
    sti[tid*4+0]=ai0; sti[tid*4+1]=ai1; sti[tid*4+2]=ai2; sti[tid*4+3]=ai3;
    __syncthreads();
    for (int off=128; off>0; off>>=1){
      if (tid<off){
        float ma=sm[tid], mb=sm[tid+off];
        float za=sz[tid], zb=sz[tid+off];
        float M = fmaxf(ma,mb);
        sz[tid] = za*expf(ma-M) + zb*expf(mb-M);
        sm[tid] = M;
        float bv0=stv[tid*4],bv1=stv[tid*4+1],bv2=stv[tid*4+2],bv3=stv[tid*4+3];
        int   bi0=sti[tid*4],bi1=sti[tid*4+1],bi2=sti[tid*4+2],bi3=sti[tid*4+3];
        #pragma unroll
        for (int q=0;q<4;++q)
          ins4(stv[(tid+off)*4+q], sti[(tid+off)*4+q],
               bv0,bv1,bv2,bv3, bi0,bi1,bi2,bi3);
        stv[tid*4]=bv0; stv[tid*4+1]=bv1; stv[tid*4+2]=bv2; stv[tid*4+3]=bv3;
        sti[tid*4]=bi0; sti[tid*4+1]=bi1; sti[tid*4+2]=bi2; sti[tid*4+3]=bi3;
      }
      __syncthreads();
    }
    if (tid==0){
      fM[k]=sm[0]; fZ[k]=sz[0];
      fV[k*4+0]=stv[0]; fV[k*4+1]=stv[1]; fV[k*4+2]=stv[2]; fV[k*4+3]=stv[3];
      fI[k*4+0]=sti[0]; fI[k*4+1]=sti[1]; fI[k*4+2]=sti[2]; fI[k*4+3]=sti[3];
    }
    __syncthreads();
  }
  if (tid==0){
    if (t==0){
      #pragma unroll
      for (int j=0;j<4;++j){
        float p = expf(fV[j]-fM[0])/fZ[0];
        scores[b*4+j] = p;
        out[j*(B_N*S_LEN) + b*S_LEN] = fI[j];
        sw[j] = fI[j];
      }
    } else {
      float cv[16]; int cj[16];
      for (int k=0;k<4;++k){
        float s = scores[b*4+k];
        #pragma unroll
        for (int j=0;j<4;++j){
          cv[k*4+j] = expf(fV[k*4+j]-fM[k])/fZ[k]*s;
          cj[k*4+j] = k*V_N + fI[k*4+j];
        }
      }
      bool used[16];
      for (int i=0;i<16;++i) used[i]=false;
      for (int rank=0;rank<4;++rank){
        int best=-1;
        for (int i=0;i<16;++i){
          if (used[i]) continue;
          if (best<0 || cv[i]>cv[best] || (cv[i]==cv[best] && cj[i]<cj[best])) best=i;
        }
        used[best]=true;
        out[rank*(B_N*S_LEN) + b*S_LEN + t] = cj[best];
        sw[rank] = cj[best] % V_N;
      }
    }
  }
  __syncthreads();
  if (t < S_LEN-1){
    const float* ein = enc_inputs  + (size_t)(t+1)*B_N*E_N + (size_t)b*E_N;
    const float* eo  = enc_outputs + (size_t)(t+1)*B_N*H_N + (size_t)b*H_N;
    #pragma unroll
    for (int j=0;j<KBEAM;++j){
      float* xr = xn + (size_t)(j*B_N + b)*D2;
      const float* em = embed + (size_t)sw[j]*E_N;
      xr[tid]       = em[tid];
      xr[E_N + tid] = ein[tid];
      #pragma unroll
      for (int q=0;q<4;++q) xr[2*E_N + q*256 + tid] = eo[q*256 + tid];
    }
  }
}

extern "C" void kernel_launch(void* const* d_in, const int* in_sizes, int n_in,
                              void* d_out, int out_size, void* d_ws, size_t ws_size,
                              hipStream_t stream) {
  (void)in_sizes; (void)n_in; (void)out_size;
  const float* enc_h_n     = (const float*)d_in[0];
  const float* enc_c_n     = (const float*)d_in[1];
  const float* enc_outputs = (const float*)d_in[2];
  const float* enc_inputs  = (const float*)d_in[3];
  const float* embed       = (const float*)d_in[4];
  const float* w_ih        = (const float*)d_in[5];
  const float* w_hh        = (const float*)d_in[6];
  const float* b_lstm      = (const float*)d_in[7];
  const float* w_out       = (const float*)d_in[8];
  const float* b_out       = (const float*)d_in[9];
  int* out = (int*)d_out;

  float* ws = (float*)d_ws;
  const size_t FRONTF = (size_t)R_N*D2*2 + (size_t)R_N*H_N + (size_t)H_N*R_N; // 458752
  const size_t PLOGF  = (size_t)LKS*R_N*V_N;    // 8,192,000
  const size_t GPARTF = (size_t)NDS*R_N*4096;   // 2,097,152
  const size_t STATF  = (size_t)R_N*NB*10;      // 320,000
  size_t need_split = (FRONTF + PLOGF + STATF + 64)*sizeof(float);
  bool use_split = (ws_size >= need_split);

  float* xA     = ws;
  float* xB     = xA + (size_t)R_N*D2;
  float* cbuf   = xB + (size_t)R_N*D2;
  float* h2t    = cbuf + (size_t)R_N*H_N;
  float* big    = h2t + (size_t)H_N*R_N;
  float* gpart  = big;                       // lifetime: k_gates -> k_lstm
  float* plog   = big;                       // lifetime: k_logits_split -> k_stats
  float *pm, *pz, *pv, *scoresb; int *pi;
  if (use_split){
    pm = big + PLOGF;
    pz = pm + (size_t)R_N*NB;
    pv = pz + (size_t)R_N*NB;
    pi = (int*)(pv + (size_t)R_N*NB*4);
    scoresb = (float*)(pi + (size_t)R_N*NB*4);
  } else {
    pm = big;                                // aliased inside gpart (disjoint lifetime)
    pz = pm + (size_t)R_N*NB;
    pv = pz + (size_t)R_N*NB;
    pi = (int*)(pv + (size_t)R_N*NB*4);
    scoresb = big + GPARTF;
  }

  k_init<<<R_N, 256, 0, stream>>>(enc_h_n, enc_c_n, enc_outputs, enc_inputs, embed, xA, cbuf);

  for (int t=0; t<S_LEN; ++t){
    float* xc = (t & 1) ? xB : xA;
    float* xn = (t & 1) ? xA : xB;
    k_gates <<<dim3(64, NDS), 256, 0, stream>>>(xc, w_ih, w_hh, gpart);
    k_lstm  <<<R_N, 256, 0, stream>>>(gpart, b_lstm, cbuf, xn, h2t);
    if (use_split){
      k_logits_split<<<dim3(LCB, LKS), 256, 0, stream>>>(h2t, w_out, plog);
      k_stats<<<NB, 256, 0, stream>>>(plog, b_out, pm, pz, pv, pi);
    } else {
      k_logits_fused<<<NB, 256, 0, stream>>>(h2t, w_out, b_out, pm, pz, pv, pi);
    }
    k_final <<<B_N, 256, 0, stream>>>(pm, pz, pv, pi, scoresb, out, t, xn,
                                      enc_inputs, enc_outputs, embed);
  }
}

// Round 11
// 4053.130 us; speedup vs baseline: 1.2816x; 1.2280x over previous
//
#include <hip/hip_runtime.h>
#include <math.h>

#define S_LEN 32
#define B_N   16
#define H_N   1024
#define E_N   256
#define V_N   32000
#define KBEAM 4
#define DIN   1536
#define D2    2560   // DIN + H_N
#define R_N   64     // KBEAM * B_N rows of state
#define NDS   8      // K-slices for gates GEMM (320 each)
#define NB    500    // logits/stats col-blocks = V_N/64
#define LKS   2      // logits K-split

__device__ __forceinline__ float sigmf(float x){ return 1.0f/(1.0f+expf(-x)); }
__device__ __forceinline__ bool better(float v1,int i1,float v2,int i2){
  return (v1>v2) || (v1==v2 && i1<i2);
}
// insert candidate (bv,bi) into sorted-desc top-4 (av0 best)
__device__ __forceinline__ void ins4(float bv,int bi,
    float&av0,float&av1,float&av2,float&av3,int&ai0,int&ai1,int&ai2,int&ai3){
  if (better(bv,bi,av3,ai3)){ av3=bv; ai3=bi;
    if (better(av3,ai3,av2,ai2)){ float t=av2;av2=av3;av3=t; int q=ai2;ai2=ai3;ai3=q;
      if (better(av2,ai2,av1,ai1)){ t=av1;av1=av2;av2=t; q=ai1;ai1=ai2;ai2=q;
        if (better(av1,ai1,av0,ai0)){ t=av0;av0=av1;av1=t; q=ai0;ai0=ai1;ai1=q; } } } }
}

// 4x4 FMA micro-tile into acc[4][4]
#define FMA16(w4, h4) { \
  acc[0][0]=fmaf(w4.x,h4.x,acc[0][0]); acc[0][1]=fmaf(w4.x,h4.y,acc[0][1]); \
  acc[0][2]=fmaf(w4.x,h4.z,acc[0][2]); acc[0][3]=fmaf(w4.x,h4.w,acc[0][3]); \
  acc[1][0]=fmaf(w4.y,h4.x,acc[1][0]); acc[1][1]=fmaf(w4.y,h4.y,acc[1][1]); \
  acc[1][2]=fmaf(w4.y,h4.z,acc[1][2]); acc[1][3]=fmaf(w4.y,h4.w,acc[1][3]); \
  acc[2][0]=fmaf(w4.z,h4.x,acc[2][0]); acc[2][1]=fmaf(w4.z,h4.y,acc[2][1]); \
  acc[2][2]=fmaf(w4.z,h4.z,acc[2][2]); acc[2][3]=fmaf(w4.z,h4.w,acc[2][3]); \
  acc[3][0]=fmaf(w4.w,h4.x,acc[3][0]); acc[3][1]=fmaf(w4.w,h4.y,acc[3][1]); \
  acc[3][2]=fmaf(w4.w,h4.z,acc[3][2]); acc[3][3]=fmaf(w4.w,h4.w,acc[3][3]); }

// ---- init: x0 = [embed[START] | enc_inputs[0] | enc_outputs[0]] , c0
__global__ __launch_bounds__(256) void k_init(
    const float* __restrict__ enc_h_n, const float* __restrict__ enc_c_n,
    const float* __restrict__ enc_outputs, const float* __restrict__ enc_inputs,
    const float* __restrict__ embed, float* __restrict__ x, float* __restrict__ c){
  int r = blockIdx.x, tid = threadIdx.x, b = r & 15;
  float* xr = x + (size_t)r*D2;
  xr[tid]        = embed[E_N + tid];                 // START token = 1
  xr[E_N + tid]  = enc_inputs[b*E_N + tid];          // t = 0
  #pragma unroll
  for (int q=0;q<4;++q) xr[2*E_N + q*256 + tid] = enc_outputs[b*H_N + q*256 + tid];
  #pragma unroll
  for (int q=0;q<4;++q) xr[DIN + q*256 + tid]   = enc_h_n[b*H_N + q*256 + tid];
  #pragma unroll
  for (int q=0;q<4;++q) c[(size_t)r*H_N + q*256 + tid] = enc_c_n[b*H_N + q*256 + tid];
}

// ---- gates GEMM (LDS double-buffered, 1 barrier/chunk): gpart[ks][64][4096]
// grid (64 col-tiles x 8 K-slices), 256 thr. Block: 64 cols x 64 rows, K=320.
#define GWLD(d, off) (*(const float4*)((((d) < DIN) ? (w_ih + (size_t)(d)*4096) \
                       : (w_hh + (size_t)((d)-DIN)*4096)) + (off)))
__global__ __launch_bounds__(256) void k_gates(
    const float* __restrict__ x, const float* __restrict__ w_ih,
    const float* __restrict__ w_hh, float* __restrict__ gpart){
  int tid = threadIdx.x;
  int jt = blockIdx.x, ks = blockIdx.y;
  int cx = tid & 15, ry = tid >> 4;
  int cb = jt*64;
  int wdd = tid >> 4, wseg = tid & 15;   // W stage: 16 dd x 16 col-segs (x2)
  int xrow = tid >> 3, xseg = tid & 7;   // X stage: 32 rows x 8 dd-segs (x2)

  __shared__ float Wt0[32][64], Wt1[32][64];
  __shared__ float Xt0[32][68], Xt1[32][68];

  float acc[4][4];
  #pragma unroll
  for (int cc=0;cc<4;++cc)
    #pragma unroll
    for (int rr=0;rr<4;++rr) acc[cc][rr]=0.f;

  int d0 = ks*320;                       // NCH = 10 chunks of 32
  const float* xp0 = x + (size_t)xrow*D2 + d0 + xseg*4;
  const float* xp1 = x + (size_t)(xrow+32)*D2 + d0 + xseg*4;

#define GLQ(WA,WB,X0,X1, ch) { int d_ = d0 + (ch)*32; \
  WA = GWLD(d_+wdd,    cb+wseg*4); \
  WB = GWLD(d_+16+wdd, cb+wseg*4); \
  X0 = *(const float4*)(xp0 + (ch)*32); \
  X1 = *(const float4*)(xp1 + (ch)*32); }
#define GSQ(Wt,Xt, WA,WB,X0,X1) { \
  *(float4*)&Wt[wdd][wseg*4]    = WA; \
  *(float4*)&Wt[wdd+16][wseg*4] = WB; \
  Xt[xseg*4+0][xrow] = X0.x; Xt[xseg*4+1][xrow] = X0.y; \
  Xt[xseg*4+2][xrow] = X0.z; Xt[xseg*4+3][xrow] = X0.w; \
  Xt[xseg*4+0][xrow+32] = X1.x; Xt[xseg*4+1][xrow+32] = X1.y; \
  Xt[xseg*4+2][xrow+32] = X1.z; Xt[xseg*4+3][xrow+32] = X1.w; }
#define GCQ(Wt,Xt) { _Pragma("unroll 8") for (int dd=0; dd<32; ++dd){ \
    float4 w4 = *(const float4*)&Wt[dd][cx*4]; \
    float4 h4 = *(const float4*)&Xt[dd][ry*4]; \
    FMA16(w4, h4) } }

  float4 wA0,wB0,x00,x10, wA1,wB1,x01,x11;
  GLQ(wA0,wB0,x00,x10, 0)
  GSQ(Wt0,Xt0, wA0,wB0,x00,x10)
  GLQ(wA1,wB1,x01,x11, 1)
  __syncthreads();

  for (int ch=0; ch<10; ch+=2){
    if (ch+2<10) GLQ(wA0,wB0,x00,x10, ch+2)
    GSQ(Wt1,Xt1, wA1,wB1,x01,x11)
    GCQ(Wt0,Xt0)
    __syncthreads();
    if (ch+3<10) GLQ(wA1,wB1,x01,x11, ch+3)
    if (ch+2<10) GSQ(Wt0,Xt0, wA0,wB0,x00,x10)
    GCQ(Wt1,Xt1)
    if (ch+2<10) __syncthreads();
  }
  #pragma unroll
  for (int rr=0;rr<4;++rr){
    float4 o; o.x=acc[0][rr]; o.y=acc[1][rr]; o.z=acc[2][rr]; o.w=acc[3][rr];
    *(float4*)&gpart[((size_t)(ks*R_N + ry*4+rr))*4096 + cb + cx*4] = o;
  }
}

// ---- LSTM: sum partials + bias, cell update; h2 -> xn[.,1536:] and h2t[1024][64]
// grid (64 rows x 4 H-quarters), 256 thr.
__global__ __launch_bounds__(256) void k_lstm(
    const float* __restrict__ gpart, const float* __restrict__ b_lstm,
    float* __restrict__ c, float* __restrict__ xn, float* __restrict__ h2t){
  int r = blockIdx.x, tid = threadIdx.x;
  int j = blockIdx.y*256 + tid;
  float gi = b_lstm[j], gf = b_lstm[1024+j], gg = b_lstm[2048+j], go = b_lstm[3072+j];
  #pragma unroll
  for (int ds=0; ds<NDS; ++ds){
    size_t base = ((size_t)ds*R_N + r)*4096;
    gi += gpart[base + j];      gf += gpart[base + 1024 + j];
    gg += gpart[base + 2048+j]; go += gpart[base + 3072 + j];
  }
  float cv = c[(size_t)r*H_N + j];
  float c2 = sigmf(gf)*cv + sigmf(gi)*tanhf(gg);
  float h2 = sigmf(go)*tanhf(c2);
  c[(size_t)r*H_N + j] = c2;
  xn[(size_t)r*D2 + DIN + j] = h2;
  h2t[(size_t)j*R_N + r] = h2;
}

// ---- logits GEMM, K-split x2 (LDS dbuf, 1 barrier/chunk) -> plog[2][64][32000]
// grid (500, 2) x 256 thr. Block: 64 cols x 64 rows x 512 dd. Thread: 4x4.
__global__ __launch_bounds__(256) void k_logits_split(
    const float* __restrict__ h2t, const float* __restrict__ w_out,
    float* __restrict__ plog){
  int tid = threadIdx.x;
  int cx  = tid & 15, ry = tid >> 4;
  int cb  = blockIdx.x * 64;
  int ks  = blockIdx.y;
  int sdd = tid >> 4, seg = tid & 15;

  __shared__ float Wt0[32][64], Wt1[32][64];
  __shared__ float Ht0[32][64], Ht1[32][64];

  float acc[4][4];
  #pragma unroll
  for (int cc=0;cc<4;++cc)
    #pragma unroll
    for (int rr=0;rr<4;++rr) acc[cc][rr]=0.f;

  const float* gW = w_out + (size_t)(ks*512 + sdd)*V_N + cb + seg*4;
  const float* gH = h2t + (size_t)(ks*512 + sdd)*64 + seg*4;

#define LLQ(WA,WB,HA,HB, ch) { \
  const float* gWn = gW + (size_t)(ch)*32*V_N; \
  const float* gHn = gH + (size_t)(ch)*32*64; \
  WA = *(const float4*)gWn; WB = *(const float4*)(gWn + (size_t)16*V_N); \
  HA = *(const float4*)gHn; HB = *(const float4*)(gHn + 16*64); }
#define LSQ(Wt,Ht, WA,WB,HA,HB) { \
  *(float4*)&Wt[sdd][seg*4]    = WA; \
  *(float4*)&Wt[sdd+16][seg*4] = WB; \
  *(float4*)&Ht[sdd][seg*4]    = HA; \
  *(float4*)&Ht[sdd+16][seg*4] = HB; }
#define LCQ(Wt,Ht) { _Pragma("unroll 8") for (int dd=0; dd<32; ++dd){ \
    float4 w4 = *(const float4*)&Wt[dd][cx*4]; \
    float4 h4 = *(const float4*)&Ht[dd][ry*4]; \
    FMA16(w4, h4) } }

  float4 wA0,wB0,hA0,hB0, wA1,wB1,hA1,hB1;
  LLQ(wA0,wB0,hA0,hB0, 0)
  LSQ(Wt0,Ht0, wA0,wB0,hA0,hB0)
  LLQ(wA1,wB1,hA1,hB1, 1)
  __syncthreads();

  for (int ch=0; ch<16; ch+=2){
    if (ch+2<16) LLQ(wA0,wB0,hA0,hB0, ch+2)
    LSQ(Wt1,Ht1, wA1,wB1,hA1,hB1)
    LCQ(Wt0,Ht0)
    __syncthreads();
    if (ch+3<16) LLQ(wA1,wB1,hA1,hB1, ch+3)
    if (ch+2<16) LSQ(Wt0,Ht0, wA0,wB0,hA0,hB0)
    LCQ(Wt1,Ht1)
    if (ch+2<16) __syncthreads();
  }

  size_t rbase = (size_t)ks*R_N;
  #pragma unroll
  for (int rr=0;rr<4;++rr){
    float4 o; o.x=acc[0][rr]; o.y=acc[1][rr]; o.z=acc[2][rr]; o.w=acc[3][rr];
    *(float4*)&plog[(rbase + ry*4+rr)*(size_t)V_N + cb + cx*4] = o;
  }
}

// ---- stats: sum the two K-halves + bias, per-row softmax stats & top-4.
// 500 blocks x 256 thr; width-16 butterfly.
__global__ __launch_bounds__(256) void k_stats(
    const float* __restrict__ plog, const float* __restrict__ b_out,
    float* __restrict__ pm, float* __restrict__ pz,
    float* __restrict__ pv, int* __restrict__ pi){
  int tid = threadIdx.x;
  int cx = tid & 15, ry = tid >> 4;
  int cb = blockIdx.x * 64;
  float4 bias = *(const float4*)&b_out[cb + cx*4];
  #pragma unroll
  for (int rr=0;rr<4;++rr){
    int row = ry*4 + rr;
    float4 a = *(const float4*)&plog[(size_t)row*V_N + cb + cx*4];
    float4 b2 = *(const float4*)&plog[(size_t)(R_N+row)*V_N + cb + cx*4];
    float v0 = a.x+b2.x+bias.x, v1 = a.y+b2.y+bias.y;
    float v2 = a.z+b2.z+bias.z, v3 = a.w+b2.w+bias.w;
    int   c0i = cb + cx*4;
    float tv0=-INFINITY,tv1=-INFINITY,tv2=-INFINITY,tv3=-INFINITY;
    int   ti0=0x7fffffff,ti1=0x7fffffff,ti2=0x7fffffff,ti3=0x7fffffff;
    ins4(v0,c0i+0,tv0,tv1,tv2,tv3,ti0,ti1,ti2,ti3);
    ins4(v1,c0i+1,tv0,tv1,tv2,tv3,ti0,ti1,ti2,ti3);
    ins4(v2,c0i+2,tv0,tv1,tv2,tv3,ti0,ti1,ti2,ti3);
    ins4(v3,c0i+3,tv0,tv1,tv2,tv3,ti0,ti1,ti2,ti3);
    float z = expf(v0-tv0)+expf(v1-tv0)+expf(v2-tv0)+expf(v3-tv0);
    #pragma unroll
    for (int msk=1; msk<16; msk<<=1){
      float om  = __shfl_xor(tv0, msk, 16);
      float oz  = __shfl_xor(z,   msk, 16);
      float ov1 = __shfl_xor(tv1, msk, 16);
      float ov2 = __shfl_xor(tv2, msk, 16);
      float ov3 = __shfl_xor(tv3, msk, 16);
      int   oi0 = __shfl_xor(ti0, msk, 16);
      int   oi1 = __shfl_xor(ti1, msk, 16);
      int   oi2 = __shfl_xor(ti2, msk, 16);
      int   oi3 = __shfl_xor(ti3, msk, 16);
      float M = fmaxf(tv0, om);
      z = z*expf(tv0-M) + oz*expf(om-M);
      ins4(om, oi0, tv0,tv1,tv2,tv3, ti0,ti1,ti2,ti3);
      ins4(ov1,oi1, tv0,tv1,tv2,tv3, ti0,ti1,ti2,ti3);
      ins4(ov2,oi2, tv0,tv1,tv2,tv3, ti0,ti1,ti2,ti3);
      ins4(ov3,oi3, tv0,tv1,tv2,tv3, ti0,ti1,ti2,ti3);
    }
    if (cx == 0){
      size_t base = (size_t)row*NB + blockIdx.x;   // [row][block]
      pm[base]=tv0; pz[base]=z;
      pv[base*4+0]=tv0; pv[base*4+1]=tv1; pv[base*4+2]=tv2; pv[base*4+3]=tv3;
      pi[base*4+0]=ti0; pi[base*4+1]=ti1; pi[base*4+2]=ti2; pi[base*4+3]=ti3;
    }
  }
}

// ---- fallback: fused logits+stats (round-6 kernel), used if ws too small.
__global__ __launch_bounds__(256) void k_logits_fused(
    const float* __restrict__ h2t, const float* __restrict__ w_out,
    const float* __restrict__ b_out,
    float* __restrict__ pm, float* __restrict__ pz,
    float* __restrict__ pv, int* __restrict__ pi){
  int tid = threadIdx.x;
  int cx  = tid & 15, ry = tid >> 4;
  int cb  = blockIdx.x * 64;
  int sdd = tid >> 4, seg = tid & 15;
  __shared__ float Wt[32][64];
  __shared__ float Ht[32][64];
  float acc[4][4];
  #pragma unroll
  for (int cc=0;cc<4;++cc)
    #pragma unroll
    for (int rr=0;rr<4;++rr) acc[cc][rr]=0.f;
  const float* gW = w_out + (size_t)sdd*V_N + cb + seg*4;
  const float* gH = h2t + sdd*64 + seg*4;
#define FLQ(WA,WB,HA,HB, ch) { \
  const float* gWn = gW + (size_t)(ch)*32*V_N; \
  const float* gHn = gH + (size_t)(ch)*32*64; \
  WA = *(const float4*)gWn; WB = *(const float4*)(gWn + (size_t)16*V_N); \
  HA = *(const float4*)gHn; HB = *(const float4*)(gHn + 16*64); }
#define FSQ(WA,WB,HA,HB) { \
  *(float4*)&Wt[sdd][seg*4]    = WA; \
  *(float4*)&Wt[sdd+16][seg*4] = WB; \
  *(float4*)&Ht[sdd][seg*4]    = HA; \
  *(float4*)&Ht[sdd+16][seg*4] = HB; }
#define FCQ() { _Pragma("unroll 8") for (int dd=0; dd<32; ++dd){ \
    float4 w4 = *(const float4*)&Wt[dd][cx*4]; \
    float4 h4 = *(const float4*)&Ht[dd][ry*4]; \
    FMA16(w4, h4) } }
  float4 wA0,wB0,hA0,hB0, wA1,wB1,hA1,hB1;
  FLQ(wA0,wB0,hA0,hB0, 0)
  FSQ(wA0,wB0,hA0,hB0)
  FLQ(wA1,wB1,hA1,hB1, 1)
  __syncthreads();
  for (int ch=0; ch<32; ch+=2){
    if (ch+2<32) FLQ(wA0,wB0,hA0,hB0, ch+2)
    FCQ()
    __syncthreads();
    FSQ(wA1,wB1,hA1,hB1)
    __syncthreads();
    if (ch+3<32) FLQ(wA1,wB1,hA1,hB1, ch+3)
    FCQ()
    if (ch+2<32){
      __syncthreads();
      FSQ(wA0,wB0,hA0,hB0)
      __syncthreads();
    }
  }
  float4 bias = *(const float4*)&b_out[cb + cx*4];
  #pragma unroll
  for (int rr=0;rr<4;++rr){
    float v0 = acc[0][rr]+bias.x, v1 = acc[1][rr]+bias.y;
    float v2 = acc[2][rr]+bias.z, v3 = acc[3][rr]+bias.w;
    int   c0i = cb + cx*4;
    float tv0=-INFINITY,tv1=-INFINITY,tv2=-INFINITY,tv3=-INFINITY;
    int   ti0=0x7fffffff,ti1=0x7fffffff,ti2=0x7fffffff,ti3=0x7fffffff;
    ins4(v0,c0i+0,tv0,tv1,tv2,tv3,ti0,ti1,ti2,ti3);
    ins4(v1,c0i+1,tv0,tv1,tv2,tv3,ti0,ti1,ti2,ti3);
    ins4(v2,c0i+2,tv0,tv1,tv2,tv3,ti0,ti1,ti2,ti3);
    ins4(v3,c0i+3,tv0,tv1,tv2,tv3,ti0,ti1,ti2,ti3);
    float z = expf(v0-tv0)+expf(v1-tv0)+expf(v2-tv0)+expf(v3-tv0);
    #pragma unroll
    for (int msk=1; msk<16; msk<<=1){
      float om  = __shfl_xor(tv0, msk, 16);
      float oz  = __shfl_xor(z,   msk, 16);
      float ov1 = __shfl_xor(tv1, msk, 16);
      float ov2 = __shfl_xor(tv2, msk, 16);
      float ov3 = __shfl_xor(tv3, msk, 16);
      int   oi0 = __shfl_xor(ti0, msk, 16);
      int   oi1 = __shfl_xor(ti1, msk, 16);
      int   oi2 = __shfl_xor(ti2, msk, 16);
      int   oi3 = __shfl_xor(ti3, msk, 16);
      float M = fmaxf(tv0, om);
      z = z*expf(tv0-M) + oz*expf(om-M);
      ins4(om, oi0, tv0,tv1,tv2,tv3, ti0,ti1,ti2,ti3);
      ins4(ov1,oi1, tv0,tv1,tv2,tv3, ti0,ti1,ti2,ti3);
      ins4(ov2,oi2, tv0,tv1,tv2,tv3, ti0,ti1,ti2,ti3);
      ins4(ov3,oi3, tv0,tv1,tv2,tv3, ti0,ti1,ti2,ti3);
    }
    if (cx == 0){
      int row = ry*4 + rr;
      size_t base = (size_t)row*NB + blockIdx.x;
      pm[base]=tv0; pz[base]=z;
      pv[base*4+0]=tv0; pv[base*4+1]=tv1; pv[base*4+2]=tv2; pv[base*4+3]=tv3;
      pi[base*4+0]=ti0; pi[base*4+1]=ti1; pi[base*4+2]=ti2; pi[base*4+3]=ti3;
    }
  }
}

// ---- final: per-beam wave reduces NB partials (shfl butterfly), joint top-4,
// write out slice t, assemble next-x. 16 blocks x 256 thr (wave k = beam k).
__global__ __launch_bounds__(256) void k_final(
    const float* __restrict__ pm, const float* __restrict__ pz,
    const float* __restrict__ pv, const int* __restrict__ pi,
    float* __restrict__ scores, int* __restrict__ out, int t,
    float* __restrict__ xn,
    const float* __restrict__ enc_inputs, const float* __restrict__ enc_outputs,
    const float* __restrict__ embed){
  int b = blockIdx.x, tid = threadIdx.x;
  int kk = tid >> 6, lane = tid & 63;
  __shared__ float fM[KBEAM], fZ[KBEAM], fV[16];
  __shared__ int   fI[16], sw[KBEAM];
  int nk = (t==0) ? 1 : KBEAM;
  if (kk < nk){
    size_t rb = (size_t)(kk*B_N + b)*NB;
    float m=-INFINITY, z=0.f;
    float av0=-INFINITY,av1=-INFINITY,av2=-INFINITY,av3=-INFINITY;
    int   ai0=0x7fffffff,ai1=0x7fffffff,ai2=0x7fffffff,ai3=0x7fffffff;
    for (int p0=lane; p0<NB; p0+=64){
      size_t p = rb + p0;
      float mf = pm[p];
      float M = fmaxf(m, mf);
      z = z*expf(m-M) + pz[p]*expf(mf-M);
      m = M;
      #pragma unroll
      for (int q=0;q<4;++q)
        ins4(pv[p*4+q], pi[p*4+q], av0,av1,av2,av3, ai0,ai1,ai2,ai3);
    }
    #pragma unroll
    for (int msk=1; msk<64; msk<<=1){
      float om  = __shfl_xor(m,   msk);
      float oz  = __shfl_xor(z,   msk);
      float ov0 = __shfl_xor(av0, msk);
      float ov1 = __shfl_xor(av1, msk);
      float ov2 = __shfl_xor(av2, msk);
      float ov3 = __shfl_xor(av3, msk);
      int   oi0 = __shfl_xor(ai0, msk);
      int   oi1 = __shfl_xor(ai1, msk);
      int   oi2 = __shfl_xor(ai2, msk);
      int   oi3 = __shfl_xor(ai3, msk);
      float M = fmaxf(m, om);
      z = z*expf(m-M) + oz*expf(om-M);
      m = M;
      ins4(ov0,oi0, av0,av1,av2,av3, ai0,ai1,ai2,ai3);
      ins4(ov1,oi1, av0,av1,av2,av3, ai0,ai1,ai2,ai3);
      ins4(ov2,oi2, av0,av1,av2,av3, ai0,ai1,ai2,ai3);
      ins4(ov3,oi3, av0,av1,av2,av3, ai0,ai1,ai2,ai3);
    }
    if (lane == 0){
      fM[kk]=m; fZ[kk]=z;
      fV[kk*4+0]=av0; fV[kk*4+1]=av1; fV[kk*4+2]=av2; fV[kk*4+3]=av3;
      fI[kk*4+0]=ai0; fI[kk*4+1]=ai1; fI[kk*4+2]=ai2; fI[kk*4+3]=ai3;
    }
  }
  __syncthreads();
  if (tid==0){
    if (t==0){
      #pragma unroll
      for (int j=0;j<4;++j){
        float p = expf(fV[j]-fM[0])/fZ[0];
        scores[b*4+j] = p;
        out[j*(B_N*S_LEN) + b*S_LEN] = fI[j];
        sw[j] = fI[j];
      }
    } else {
      float cv[16]; int cj[16];
      for (int k=0;k<4;++k){
        float s = scores[b*4+k];
        #pragma unroll
        for (int j=0;j<4;++j){
          cv[k*4+j] = expf(fV[k*4+j]-fM[k])/fZ[k]*s;
          cj[k*4+j] = k*V_N + fI[k*4+j];
        }
      }
      bool used[16];
      for (int i=0;i<16;++i) used[i]=false;
      for (int rank=0;rank<4;++rank){
        int best=-1;
        for (int i=0;i<16;++i){
          if (used[i]) continue;
          if (best<0 || cv[i]>cv[best] || (cv[i]==cv[best] && cj[i]<cj[best])) best=i;
        }
        used[best]=true;
        out[rank*(B_N*S_LEN) + b*S_LEN + t] = cj[best];
        sw[rank] = cj[best] % V_N;
      }
    }
  }
  __syncthreads();
  if (t < S_LEN-1){
    const float* ein = enc_inputs  + (size_t)(t+1)*B_N*E_N + (size_t)b*E_N;
    const float* eo  = enc_outputs + (size_t)(t+1)*B_N*H_N + (size_t)b*H_N;
    #pragma unroll
    for (int j=0;j<KBEAM;++j){
      float* xr = xn + (size_t)(j*B_N + b)*D2;
      const float* em = embed + (size_t)sw[j]*E_N;
      xr[tid]       = em[tid];
      xr[E_N + tid] = ein[tid];
      #pragma unroll
      for (int q=0;q<4;++q) xr[2*E_N + q*256 + tid] = eo[q*256 + tid];
    }
  }
}

extern "C" void kernel_launch(void* const* d_in, const int* in_sizes, int n_in,
                              void* d_out, int out_size, void* d_ws, size_t ws_size,
                              hipStream_t stream) {
  (void)in_sizes; (void)n_in; (void)out_size;
  const float* enc_h_n     = (const float*)d_in[0];
  const float* enc_c_n     = (const float*)d_in[1];
  const float* enc_outputs = (const float*)d_in[2];
  const float* enc_inputs  = (const float*)d_in[3];
  const float* embed       = (const float*)d_in[4];
  const float* w_ih        = (const float*)d_in[5];
  const float* w_hh        = (const float*)d_in[6];
  const float* b_lstm      = (const float*)d_in[7];
  const float* w_out       = (const float*)d_in[8];
  const float* b_out       = (const float*)d_in[9];
  int* out = (int*)d_out;

  float* ws = (float*)d_ws;
  const size_t FRONTF = (size_t)R_N*D2*2 + (size_t)R_N*H_N + (size_t)H_N*R_N; // 458752
  const size_t PLOGF  = (size_t)LKS*R_N*V_N;    // 4,096,000
  const size_t GPARTF = (size_t)NDS*R_N*4096;   // 2,097,152
  const size_t STATF  = (size_t)R_N*NB*10;      // 320,000
  size_t need_split = (FRONTF + PLOGF + STATF + 64)*sizeof(float);
  bool use_split = (ws_size >= need_split);

  float* xA     = ws;
  float* xB     = xA + (size_t)R_N*D2;
  float* cbuf   = xB + (size_t)R_N*D2;
  float* h2t    = cbuf + (size_t)R_N*H_N;
  float* big    = h2t + (size_t)H_N*R_N;
  float* gpart  = big;                       // lifetime: k_gates -> k_lstm
  float* plog   = big;                       // lifetime: k_logits_split -> k_stats
  float *pm, *pz, *pv, *scoresb; int *pi;
  if (use_split){
    pm = big + PLOGF;
    pz = pm + (size_t)R_N*NB;
    pv = pz + (size_t)R_N*NB;
    pi = (int*)(pv + (size_t)R_N*NB*4);
    scoresb = (float*)(pi + (size_t)R_N*NB*4);
  } else {
    pm = big;                                // aliased inside gpart (disjoint lifetime)
    pz = pm + (size_t)R_N*NB;
    pv = pz + (size_t)R_N*NB;
    pi = (int*)(pv + (size_t)R_N*NB*4);
    scoresb = big + GPARTF;
  }

  k_init<<<R_N, 256, 0, stream>>>(enc_h_n, enc_c_n, enc_outputs, enc_inputs, embed, xA, cbuf);

  for (int t=0; t<S_LEN; ++t){
    float* xc = (t & 1) ? xB : xA;
    float* xn = (t & 1) ? xA : xB;
    k_gates <<<dim3(64, NDS), 256, 0, stream>>>(xc, w_ih, w_hh, gpart);
    k_lstm  <<<dim3(R_N, 4), 256, 0, stream>>>(gpart, b_lstm, cbuf, xn, h2t);
    if (use_split){
      k_logits_split<<<dim3(NB, LKS), 256, 0, stream>>>(h2t, w_out, plog);
      k_stats<<<NB, 256, 0, stream>>>(plog, b_out, pm, pz, pv, pi);
    } else {
      k_logits_fused<<<NB, 256, 0, stream>>>(h2t, w_out, b_out, pm, pz, pv, pi);
    }
    k_final <<<B_N, 256, 0, stream>>>(pm, pz, pv, pi, scoresb, out, t, xn,
                                      enc_inputs, enc_outputs, embed);
  }
}